// Round 1
// baseline (1087.015 us; speedup 1.0000x reference)
//
#include <hip/hip_runtime.h>
#include <math.h>

#define CUTR 5.0f
#define TL 4096
#define NBASIS 32

__device__ __forceinline__ float silu_f(float x) { return x / (1.0f + expf(-x)); }

// ---------------- scalar init from embedding ----------------
__global__ void emb_kernel(const int* __restrict__ z, const float* __restrict__ emb,
                           float* __restrict__ scalar, int N) {
  int idx = blockIdx.x * 256 + threadIdx.x;
  if (idx >= N * 128) return;
  int n = idx >> 7, j = idx & 127;
  scalar[idx] = emb[z[n] * 128 + j];
}

// ---------------- radial filter table: T2(len)[j] = g*(g*(rbf@f_w)[j] + f_b[j]) ----------------
__global__ void table_kernel(const float* __restrict__ f_w, const float* __restrict__ f_b,
                             float* __restrict__ tab) {
  int idx = blockIdx.x * 256 + threadIdx.x;  // l*TL*384 + t*384 + j
  int j = idx % 384;
  int t = (idx / 384) % TL;
  int l = idx / (384 * TL);
  if (l >= 3) return;
  float len = (float)t * (CUTR / (float)(TL - 1));
  float s = len * (1.0f / CUTR);
  float g = 0.0f;
  if (s < 1.0f) g = expf(1.0f - 1.0f / (1.0f - s * s));
  const float gamma = (31.0f / 5.0f) * (31.0f / 5.0f);
  float acc = 0.0f;
  const float* fw = f_w + (size_t)l * NBASIS * 384 + j;
#pragma unroll
  for (int k = 0; k < NBASIS; k++) {
    float c = 5.0f * (float)k / 31.0f;
    float d = len - c;
    acc += expf(-gamma * d * d) * fw[k * 384];
  }
  tab[idx] = g * (g * acc + f_b[l * 384 + j]);
}

// ---------------- CSR build over ACTIVE edges (len < CUT) ----------------
__global__ void count_kernel(const float* __restrict__ pos, const int* __restrict__ ei,
                             const float* __restrict__ shifts, int* __restrict__ counts, int E) {
  int e = blockIdx.x * 256 + threadIdx.x;
  if (e >= E) return;
  int r = ei[e], c = ei[E + e];
  float dx = pos[c * 3 + 0] - pos[r * 3 + 0] + shifts[e * 3 + 0];
  float dy = pos[c * 3 + 1] - pos[r * 3 + 1] + shifts[e * 3 + 1];
  float dz = pos[c * 3 + 2] - pos[r * 3 + 2] + shifts[e * 3 + 2];
  float len = sqrtf(dx * dx + dy * dy + dz * dz + 1e-12f);
  if (len < CUTR) atomicAdd(&counts[r], 1);
}

__global__ __launch_bounds__(1024) void scan_kernel(const int* __restrict__ counts,
                                                    int* __restrict__ offs,
                                                    int* __restrict__ cursor, int N) {
  __shared__ int sm[1024];
  int tid = threadIdx.x;
  int CH = (N + 1023) / 1024;
  int base = tid * CH;
  int sum = 0;
  for (int i = 0; i < CH; i++) sum += (base + i < N) ? counts[base + i] : 0;
  sm[tid] = sum;
  __syncthreads();
  for (int o = 1; o < 1024; o <<= 1) {
    int v = (tid >= o) ? sm[tid - o] : 0;
    __syncthreads();
    sm[tid] += v;
    __syncthreads();
  }
  int run = sm[tid] - sum;  // exclusive base of my chunk
  for (int i = 0; i < CH; i++) {
    if (base + i < N) {
      offs[base + i] = run;
      cursor[base + i] = run;
      run += counts[base + i];
    }
  }
  if (tid == 1023) offs[N] = sm[1023];
}

__global__ void fill_kernel(const float* __restrict__ pos, const int* __restrict__ ei,
                            const float* __restrict__ shifts, int* __restrict__ cursor,
                            float4* __restrict__ pk, int E) {
  int e = blockIdx.x * 256 + threadIdx.x;
  if (e >= E) return;
  int r = ei[e], c = ei[E + e];
  float dx = pos[c * 3 + 0] - pos[r * 3 + 0] + shifts[e * 3 + 0];
  float dy = pos[c * 3 + 1] - pos[r * 3 + 1] + shifts[e * 3 + 1];
  float dz = pos[c * 3 + 2] - pos[r * 3 + 2] + shifts[e * 3 + 2];
  float len = sqrtf(dx * dx + dy * dy + dz * dz + 1e-12f);
  if (len >= CUTR) return;  // gate == 0 -> zero message, skip entirely
  float inv = 1.0f / len;
  float x = len * ((float)(TL - 1) / CUTR);
  int ib = (int)x;
  if (ib > TL - 2) ib = TL - 2;
  float fr = x - (float)ib;
  int p = atomicAdd(&cursor[r], 1);
  pk[2 * p] = make_float4(__int_as_float(c), fr, __int_as_float(ib), 0.0f);
  pk[2 * p + 1] = make_float4(dx * inv, dy * inv, dz * inv, 0.0f);
}

// ---------------- fused message: one wave per destination node ----------------
__global__ __launch_bounds__(256) void message_kernel(
    const int* __restrict__ offs, const float4* __restrict__ pk, const float* __restrict__ hn,
    const float* __restrict__ vin, const float* __restrict__ tab, float* __restrict__ scalar,
    float* __restrict__ vout, int N) {
  int lane = threadIdx.x & 63;
  int n = blockIdx.x * 4 + (threadIdx.x >> 6);
  if (n >= N) return;
  int p0 = offs[n], p1 = offs[n + 1];
  float aS0 = 0.f, aS1 = 0.f;
  float aV00 = 0.f, aV01 = 0.f, aV10 = 0.f, aV11 = 0.f, aV20 = 0.f, aV21 = 0.f;
  for (int p = p0; p < p1; ++p) {
    float4 r0 = pk[2 * p];
    float4 r1 = pk[2 * p + 1];
    int col = __float_as_int(r0.x);
    float fr = r0.y;
    int ib = __float_as_int(r0.z);
    const float* hb = hn + (size_t)col * 384;
    const float* vb = vin + (size_t)col * 384;
    const float* tb = tab + (size_t)ib * 384;
    {
      int jj = lane;
      float t00 = tb[jj], t10 = tb[jj + 384];
      float t01 = tb[jj + 128], t11 = tb[jj + 512];
      float t02 = tb[jj + 256], t12 = tb[jj + 640];
      float ft1 = t00 + fr * (t10 - t00);
      float ft2 = t01 + fr * (t11 - t01);
      float ft3 = t02 + fr * (t12 - t02);
      float w1 = hb[jj] * ft1, w2 = hb[jj + 128] * ft2, w3 = hb[jj + 256] * ft3;
      aS0 += w1;
      aV00 += vb[jj] * w2 + w3 * r1.x;
      aV10 += vb[jj + 128] * w2 + w3 * r1.y;
      aV20 += vb[jj + 256] * w2 + w3 * r1.z;
    }
    {
      int jj = lane + 64;
      float t00 = tb[jj], t10 = tb[jj + 384];
      float t01 = tb[jj + 128], t11 = tb[jj + 512];
      float t02 = tb[jj + 256], t12 = tb[jj + 640];
      float ft1 = t00 + fr * (t10 - t00);
      float ft2 = t01 + fr * (t11 - t01);
      float ft3 = t02 + fr * (t12 - t02);
      float w1 = hb[jj] * ft1, w2 = hb[jj + 128] * ft2, w3 = hb[jj + 256] * ft3;
      aS1 += w1;
      aV01 += vb[jj] * w2 + w3 * r1.x;
      aV11 += vb[jj + 128] * w2 + w3 * r1.y;
      aV21 += vb[jj + 256] * w2 + w3 * r1.z;
    }
  }
  size_t sb = (size_t)n * 128 + lane;
  scalar[sb] += aS0;
  scalar[sb + 64] += aS1;
  size_t vb0 = (size_t)n * 384 + lane;
  vout[vb0] = vin[vb0] + aV00;
  vout[vb0 + 64] = vin[vb0 + 64] + aV01;
  vout[vb0 + 128] = vin[vb0 + 128] + aV10;
  vout[vb0 + 192] = vin[vb0 + 192] + aV11;
  vout[vb0 + 256] = vin[vb0 + 256] + aV20;
  vout[vb0 + 320] = vin[vb0 + 320] + aV21;
}

// ---------------- generic fp32 tiled GEMM: C = act(A[M,K] @ W[K,N] + b) ----------------
template <bool SILU, bool HASB>
__global__ __launch_bounds__(256) void gemm_kernel(const float* __restrict__ A,
                                                   const float* __restrict__ W,
                                                   const float* __restrict__ bias,
                                                   float* __restrict__ C, int M, int K, int Nn) {
  __shared__ float As[32][68];
  __shared__ float Ws[32][68];
  int tid = threadIdx.x;
  int m0 = blockIdx.x * 64, n0 = blockIdx.y * 64;
  int ty = tid >> 4, tx = tid & 15;
  float acc[4][4] = {{0.f}};
  int la_m = tid >> 2;        // 0..63
  int la_k = (tid & 3) * 8;   // 0,8,16,24
  int lw_k = tid >> 3;        // 0..31
  int lw_n = (tid & 7) * 8;   // 0..56

  for (int k0 = 0; k0 < K; k0 += 32) {
    float4 a0 = {0, 0, 0, 0}, a1 = {0, 0, 0, 0};
    if (m0 + la_m < M) {
      const float* ap = A + (size_t)(m0 + la_m) * K + k0 + la_k;
      a0 = *(const float4*)ap;
      a1 = *(const float4*)(ap + 4);
    }
    const float* wp = W + (size_t)(k0 + lw_k) * Nn + n0 + lw_n;
    float4 w0 = *(const float4*)wp;
    float4 w1 = *(const float4*)(wp + 4);
    __syncthreads();
    As[la_k + 0][la_m] = a0.x; As[la_k + 1][la_m] = a0.y;
    As[la_k + 2][la_m] = a0.z; As[la_k + 3][la_m] = a0.w;
    As[la_k + 4][la_m] = a1.x; As[la_k + 5][la_m] = a1.y;
    As[la_k + 6][la_m] = a1.z; As[la_k + 7][la_m] = a1.w;
    Ws[lw_k][lw_n + 0] = w0.x; Ws[lw_k][lw_n + 1] = w0.y;
    Ws[lw_k][lw_n + 2] = w0.z; Ws[lw_k][lw_n + 3] = w0.w;
    Ws[lw_k][lw_n + 4] = w1.x; Ws[lw_k][lw_n + 5] = w1.y;
    Ws[lw_k][lw_n + 6] = w1.z; Ws[lw_k][lw_n + 7] = w1.w;
    __syncthreads();
#pragma unroll
    for (int k = 0; k < 32; k++) {
      float4 av = *(const float4*)&As[k][ty * 4];
      float4 bv = *(const float4*)&Ws[k][tx * 4];
      acc[0][0] += av.x * bv.x; acc[0][1] += av.x * bv.y; acc[0][2] += av.x * bv.z; acc[0][3] += av.x * bv.w;
      acc[1][0] += av.y * bv.x; acc[1][1] += av.y * bv.y; acc[1][2] += av.y * bv.z; acc[1][3] += av.y * bv.w;
      acc[2][0] += av.z * bv.x; acc[2][1] += av.z * bv.y; acc[2][2] += av.z * bv.z; acc[2][3] += av.z * bv.w;
      acc[3][0] += av.w * bv.x; acc[3][1] += av.w * bv.y; acc[3][2] += av.w * bv.z; acc[3][3] += av.w * bv.w;
    }
  }
#pragma unroll
  for (int i = 0; i < 4; i++) {
    int m = m0 + ty * 4 + i;
    if (m >= M) continue;
    float4 o;
    float v0 = acc[i][0] + (HASB ? bias[n0 + tx * 4 + 0] : 0.f);
    float v1 = acc[i][1] + (HASB ? bias[n0 + tx * 4 + 1] : 0.f);
    float v2 = acc[i][2] + (HASB ? bias[n0 + tx * 4 + 2] : 0.f);
    float v3 = acc[i][3] + (HASB ? bias[n0 + tx * 4 + 3] : 0.f);
    if (SILU) { v0 = silu_f(v0); v1 = silu_f(v1); v2 = silu_f(v2); v3 = silu_f(v3); }
    o.x = v0; o.y = v1; o.z = v2; o.w = v3;
    *(float4*)(C + (size_t)m * Nn + n0 + tx * 4) = o;
  }
}

// ---------------- v_norm + concat(scalar, v_norm) ----------------
__global__ void vnorm_kernel(const float* __restrict__ vv, const float* __restrict__ scalar,
                             float* __restrict__ cat, int N) {
  int idx = blockIdx.x * 256 + threadIdx.x;
  if (idx >= N * 128) return;
  int n = idx >> 7, j = idx & 127;
  size_t b = (size_t)n * 384 + j;
  float v0 = vv[b], v1 = vv[b + 128], v2 = vv[b + 256];
  float vn = sqrtf(v0 * v0 + v1 * v1 + v2 * v2 + 1e-8f);
  cat[(size_t)n * 256 + j] = scalar[idx];
  cat[(size_t)n * 256 + 128 + j] = vn;
}

// ---------------- update combine ----------------
__global__ void combine_kernel(const float* __restrict__ uv, const float* __restrict__ vv,
                               const float* __restrict__ a, float* __restrict__ scalar,
                               float* __restrict__ vec, int N) {
  int idx = blockIdx.x * 256 + threadIdx.x;
  if (idx >= N * 128) return;
  int n = idx >> 7, j = idx & 127;
  size_t b = (size_t)n * 384 + j;
  float u0 = uv[b], u1 = uv[b + 128], u2 = uv[b + 256];
  float w0 = vv[b], w1 = vv[b + 128], w2 = vv[b + 256];
  float dot = u0 * w0 + u1 * w1 + u2 * w2;
  float a1 = a[b], a2 = a[b + 128], a3 = a[b + 256];
  scalar[idx] += a1 + a2 * dot;
  vec[b] += a3 * u0;
  vec[b + 128] += a3 * u1;
  vec[b + 256] += a3 * u2;
}

// ---------------- readout: e_atom dot + segment sum ----------------
__global__ void readout_kernel(const float* __restrict__ t3, const float* __restrict__ r_w2,
                               const float* __restrict__ r_b2, const int* __restrict__ bidx,
                               float* __restrict__ out, int N) {
  int lane = threadIdx.x & 63;
  int n = blockIdx.x * 4 + (threadIdx.x >> 6);
  if (n >= N) return;
  float v = t3[(size_t)n * 64 + lane] * r_w2[lane];
#pragma unroll
  for (int o = 32; o > 0; o >>= 1) v += __shfl_down(v, o);
  if (lane == 0) atomicAdd(&out[bidx[n]], v + r_b2[0]);
}

extern "C" void kernel_launch(void* const* d_in, const int* in_sizes, int n_in, void* d_out,
                              int out_size, void* d_ws, size_t ws_size, hipStream_t stream) {
  const int N = in_sizes[0];
  const int E = in_sizes[2] / 2;
  const int G = out_size;

  const int* z = (const int*)d_in[0];
  const float* pos = (const float*)d_in[1];
  const int* ei = (const int*)d_in[2];
  const float* shifts = (const float*)d_in[3];
  const int* bidx = (const int*)d_in[4];
  const float* emb = (const float*)d_in[5];
  const float* m_w1 = (const float*)d_in[6];
  const float* m_b1 = (const float*)d_in[7];
  const float* m_w2 = (const float*)d_in[8];
  const float* m_b2 = (const float*)d_in[9];
  const float* f_w = (const float*)d_in[10];
  const float* f_b = (const float*)d_in[11];
  const float* u_w = (const float*)d_in[12];
  const float* v_w = (const float*)d_in[13];
  const float* up_w1 = (const float*)d_in[14];
  const float* up_b1 = (const float*)d_in[15];
  const float* up_w2 = (const float*)d_in[16];
  const float* up_b2 = (const float*)d_in[17];
  const float* r_w1 = (const float*)d_in[18];
  const float* r_b1 = (const float*)d_in[19];
  const float* r_w2 = (const float*)d_in[20];
  const float* r_b2 = (const float*)d_in[21];
  float* out = (float*)d_out;

  float* w = (float*)d_ws;
  size_t off = 0;
  auto alloc = [&](size_t nfl) { float* p = w + off; off += nfl; return p; };
  float* tab = alloc((size_t)3 * TL * 384);
  float* scalar = alloc((size_t)N * 128);
  float* vecA = alloc((size_t)N * 384);
  float* vecB = alloc((size_t)N * 384);
  float* hn = alloc((size_t)N * 384);  // reused as 'a'
  float* t1 = alloc((size_t)N * 128);  // reused as t2
  float* cat = alloc((size_t)N * 256);
  float* uv = alloc((size_t)N * 384);
  float* vv = alloc((size_t)N * 384);
  float* t3 = alloc((size_t)N * 64);
  float* pkf = alloc((size_t)E * 8);  // 2x float4 per active edge
  int* counts = (int*)alloc((size_t)N);
  int* offs = (int*)alloc((size_t)N + 4);
  int* cursor = (int*)alloc((size_t)N);
  if (off * sizeof(float) > ws_size) return;  // workspace too small -> loud failure

  hipMemsetAsync(counts, 0, (size_t)N * sizeof(int), stream);
  hipMemsetAsync(vecA, 0, (size_t)N * 384 * sizeof(float), stream);
  hipMemsetAsync(out, 0, (size_t)G * sizeof(float), stream);

  emb_kernel<<<(N * 128 + 255) / 256, 256, 0, stream>>>(z, emb, scalar, N);
  table_kernel<<<(3 * TL * 384 + 255) / 256, 256, 0, stream>>>(f_w, f_b, tab);
  count_kernel<<<(E + 255) / 256, 256, 0, stream>>>(pos, ei, shifts, counts, E);
  scan_kernel<<<1, 1024, 0, stream>>>(counts, offs, cursor, N);
  fill_kernel<<<(E + 255) / 256, 256, 0, stream>>>(pos, ei, shifts, cursor, (float4*)pkf, E);

  dim3 g1((N + 63) / 64, 2);       // [N,128]x[128,128]
  dim3 g2((N + 63) / 64, 6);       // [N,128]x[128,384]
  dim3 g3((3 * N + 63) / 64, 2);   // [3N,128]x[128,128]
  dim3 gr((N + 63) / 64, 1);       // [N,128]x[128,64]
  int ge = (N * 128 + 255) / 256;

  for (int l = 0; l < 3; l++) {
    const float* cur = (l & 1) ? vecB : vecA;
    float* nxt = (l & 1) ? vecA : vecB;
    gemm_kernel<true, true><<<g1, 256, 0, stream>>>(scalar, m_w1 + (size_t)l * 16384,
                                                    m_b1 + l * 128, t1, N, 128, 128);
    gemm_kernel<false, true><<<g2, 256, 0, stream>>>(t1, m_w2 + (size_t)l * 49152,
                                                     m_b2 + l * 384, hn, N, 128, 384);
    message_kernel<<<(N + 3) / 4, 256, 0, stream>>>(offs, (const float4*)pkf, hn, cur,
                                                    tab + (size_t)l * TL * 384, scalar, nxt, N);
    gemm_kernel<false, false><<<g3, 256, 0, stream>>>(nxt, u_w + (size_t)l * 16384, nullptr, uv,
                                                      3 * N, 128, 128);
    gemm_kernel<false, false><<<g3, 256, 0, stream>>>(nxt, v_w + (size_t)l * 16384, nullptr, vv,
                                                      3 * N, 128, 128);
    vnorm_kernel<<<ge, 256, 0, stream>>>(vv, scalar, cat, N);
    gemm_kernel<true, true><<<g1, 256, 0, stream>>>(cat, up_w1 + (size_t)l * 32768,
                                                    up_b1 + l * 128, t1, N, 256, 128);
    gemm_kernel<false, true><<<g2, 256, 0, stream>>>(t1, up_w2 + (size_t)l * 49152,
                                                     up_b2 + l * 384, hn, N, 128, 384);
    combine_kernel<<<ge, 256, 0, stream>>>(uv, vv, hn, scalar, nxt, N);
  }

  gemm_kernel<true, true><<<gr, 256, 0, stream>>>(scalar, r_w1, r_b1, t3, N, 128, 64);
  readout_kernel<<<(N + 3) / 4, 256, 0, stream>>>(t3, r_w2, r_b2, bidx, out, N);
}

// Round 2
// 626.909 us; speedup vs baseline: 1.7339x; 1.7339x over previous
//
#include <hip/hip_runtime.h>
#include <math.h>

#define CUTR 5.0f
#define TL 2048
#define NBASIS 32

typedef __attribute__((ext_vector_type(8))) short bf16x8;
typedef __attribute__((ext_vector_type(4))) float f32x4;

__device__ __forceinline__ float silu_f(float x) { return x / (1.0f + expf(-x)); }
__device__ __forceinline__ ushort f2bf(float x) {
  uint b = __float_as_uint(x);
  uint r = (b + 0x7FFFu + ((b >> 16) & 1u)) >> 16;
  return (ushort)r;
}
#define BFLO(u) __uint_as_float((u) << 16)
#define BFHI(u) __uint_as_float((u) & 0xFFFF0000u)

// ---------------- scalar init from embedding ----------------
__global__ void emb_kernel(const int* __restrict__ z, const float* __restrict__ emb,
                           float* __restrict__ scalar, ushort* __restrict__ sbf, int N) {
  int idx = blockIdx.x * 256 + threadIdx.x;
  if (idx >= N * 128) return;
  int n = idx >> 7, j = idx & 127;
  float v = emb[z[n] * 128 + j];
  scalar[idx] = v;
  sbf[idx] = f2bf(v);
}

// ---------------- weight convert + transpose to bf16 [N][K] ----------------
// layout (ushort): per layer l (stride 180224): m1@0(16384) m2@16384(49152)
// uv@65536(32768) up1@98304(32768) up2@131072(49152); r1 @ 540672(8192)
__global__ void wconv_kernel(const float* __restrict__ m_w1, const float* __restrict__ m_w2,
                             const float* __restrict__ u_w, const float* __restrict__ v_w,
                             const float* __restrict__ up_w1, const float* __restrict__ up_w2,
                             const float* __restrict__ r_w1, ushort* __restrict__ wt) {
  int idx = blockIdx.x * 256 + threadIdx.x;
  if (idx >= 548864) return;
  float v;
  if (idx >= 540672) {
    int t = idx - 540672;
    int n = t >> 7, k = t & 127;
    v = r_w1[k * 64 + n];
  } else {
    int l = idx / 180224, local = idx % 180224;
    if (local < 16384) {
      int n = local >> 7, k = local & 127;
      v = m_w1[l * 16384 + k * 128 + n];
    } else if (local < 65536) {
      int t = local - 16384;
      int n = t >> 7, k = t & 127;
      v = m_w2[l * 49152 + k * 384 + n];
    } else if (local < 98304) {
      int t = local - 65536;
      int n = t >> 7, k = t & 127;
      v = (n < 128) ? u_w[l * 16384 + k * 128 + n] : v_w[l * 16384 + k * 128 + (n - 128)];
    } else if (local < 131072) {
      int t = local - 98304;
      int n = t >> 8, k = t & 255;
      v = up_w1[l * 32768 + k * 128 + n];
    } else {
      int t = local - 131072;
      int n = t >> 7, k = t & 127;
      v = up_w2[l * 49152 + k * 384 + n];
    }
  }
  wt[idx] = f2bf(v);
}

// ---------------- radial filter table (bf16): T2(len)[j] = g*(g*(rbf@f_w)[j]+f_b[j]) ----
__global__ void table_kernel(const float* __restrict__ f_w, const float* __restrict__ f_b,
                             ushort* __restrict__ tab) {
  int idx = blockIdx.x * 256 + threadIdx.x;
  if (idx >= 3 * TL * 384) return;
  int j = idx % 384;
  int t = (idx / 384) % TL;
  int l = idx / (384 * TL);
  float len = (float)t * (CUTR / (float)(TL - 1));
  float s = len * (1.0f / CUTR);
  float g = 0.0f;
  if (s < 1.0f) g = expf(1.0f - 1.0f / (1.0f - s * s));
  const float gamma = (31.0f / 5.0f) * (31.0f / 5.0f);
  float acc = 0.0f;
  const float* fw = f_w + (size_t)l * NBASIS * 384 + j;
#pragma unroll
  for (int k = 0; k < NBASIS; k++) {
    float c = 5.0f * (float)k / 31.0f;
    float d = len - c;
    acc += expf(-gamma * d * d) * fw[k * 384];
  }
  tab[idx] = f2bf(g * (g * acc + f_b[l * 384 + j]));
}

// ---------------- CSR build over ACTIVE edges (len < CUT) ----------------
__global__ void count_kernel(const float* __restrict__ pos, const int* __restrict__ ei,
                             const float* __restrict__ shifts, int* __restrict__ counts, int E) {
  int e = blockIdx.x * 256 + threadIdx.x;
  if (e >= E) return;
  int r = ei[e], c = ei[E + e];
  float dx = pos[c * 3 + 0] - pos[r * 3 + 0] + shifts[e * 3 + 0];
  float dy = pos[c * 3 + 1] - pos[r * 3 + 1] + shifts[e * 3 + 1];
  float dz = pos[c * 3 + 2] - pos[r * 3 + 2] + shifts[e * 3 + 2];
  float len = sqrtf(dx * dx + dy * dy + dz * dz + 1e-12f);
  if (len < CUTR) atomicAdd(&counts[r], 1);
}

__global__ __launch_bounds__(1024) void scan_kernel(const int* __restrict__ counts,
                                                    int* __restrict__ offs,
                                                    int* __restrict__ cursor, int N) {
  __shared__ int sm[1024];
  int tid = threadIdx.x;
  int CH = (N + 1023) / 1024;
  int base = tid * CH;
  int sum = 0;
  for (int i = 0; i < CH; i++) sum += (base + i < N) ? counts[base + i] : 0;
  sm[tid] = sum;
  __syncthreads();
  for (int o = 1; o < 1024; o <<= 1) {
    int v = (tid >= o) ? sm[tid - o] : 0;
    __syncthreads();
    sm[tid] += v;
    __syncthreads();
  }
  int run = sm[tid] - sum;
  for (int i = 0; i < CH; i++) {
    if (base + i < N) {
      offs[base + i] = run;
      cursor[base + i] = run;
      run += counts[base + i];
    }
  }
  if (tid == 1023) offs[N] = sm[1023];
}

__global__ void fill_kernel(const float* __restrict__ pos, const int* __restrict__ ei,
                            const float* __restrict__ shifts, int* __restrict__ cursor,
                            float4* __restrict__ pk, int E) {
  int e = blockIdx.x * 256 + threadIdx.x;
  if (e >= E) return;
  int r = ei[e], c = ei[E + e];
  float dx = pos[c * 3 + 0] - pos[r * 3 + 0] + shifts[e * 3 + 0];
  float dy = pos[c * 3 + 1] - pos[r * 3 + 1] + shifts[e * 3 + 1];
  float dz = pos[c * 3 + 2] - pos[r * 3 + 2] + shifts[e * 3 + 2];
  float len = sqrtf(dx * dx + dy * dy + dz * dz + 1e-12f);
  if (len >= CUTR) return;
  float inv = 1.0f / len;
  float x = len * ((float)(TL - 1) / CUTR);
  int ib = (int)x;
  if (ib > TL - 2) ib = TL - 2;
  float fr = x - (float)ib;
  int p = atomicAdd(&cursor[r], 1);
  pk[2 * p] = make_float4(__int_as_float(c), fr, __int_as_float(ib), 0.0f);
  pk[2 * p + 1] = make_float4(dx * inv, dy * inv, dz * inv, 0.0f);
}

// ---------------- fused message: one wave per destination node, bf16 gathers ----------------
__global__ __launch_bounds__(256) void message_kernel(
    const int* __restrict__ offs, const float4* __restrict__ pk, const uint* __restrict__ hn,
    const uint* __restrict__ vbin, const uint* __restrict__ tab, float* __restrict__ scalar,
    float* __restrict__ vec, ushort* __restrict__ vbout, int N) {
  int lane = threadIdx.x & 63;
  int n = blockIdx.x * 4 + (threadIdx.x >> 6);
  if (n >= N) return;
  int p0 = offs[n], p1 = offs[n + 1];
  float aS0 = 0.f, aS1 = 0.f;
  float aV00 = 0.f, aV01 = 0.f, aV10 = 0.f, aV11 = 0.f, aV20 = 0.f, aV21 = 0.f;
  for (int p = p0; p < p1; ++p) {
    float4 r0 = pk[2 * p];
    float4 r1 = pk[2 * p + 1];
    int col = __float_as_int(r0.x);
    float fr = r0.y;
    int ib = __float_as_int(r0.z);
    const uint* hb = hn + (size_t)col * 192;
    const uint* vb = vbin + (size_t)col * 192;
    const uint* tb = tab + (size_t)ib * 192;
    uint h1u = hb[lane], h2u = hb[lane + 64], h3u = hb[lane + 128];
    uint v0u = vb[lane], v1u = vb[lane + 64], v2u = vb[lane + 128];
    uint ta0 = tb[lane], tb0 = tb[lane + 64], tc0 = tb[lane + 128];
    uint ta1 = tb[lane + 192], tb1 = tb[lane + 256], tc1 = tb[lane + 320];
    float f1l = BFLO(ta0) + fr * (BFLO(ta1) - BFLO(ta0));
    float f1h = BFHI(ta0) + fr * (BFHI(ta1) - BFHI(ta0));
    float f2l = BFLO(tb0) + fr * (BFLO(tb1) - BFLO(tb0));
    float f2h = BFHI(tb0) + fr * (BFHI(tb1) - BFHI(tb0));
    float f3l = BFLO(tc0) + fr * (BFLO(tc1) - BFLO(tc0));
    float f3h = BFHI(tc0) + fr * (BFHI(tc1) - BFHI(tc0));
    float w1l = BFLO(h1u) * f1l, w1h = BFHI(h1u) * f1h;
    float w2l = BFLO(h2u) * f2l, w2h = BFHI(h2u) * f2h;
    float w3l = BFLO(h3u) * f3l, w3h = BFHI(h3u) * f3h;
    aS0 += w1l;
    aS1 += w1h;
    aV00 += BFLO(v0u) * w2l + w3l * r1.x;
    aV01 += BFHI(v0u) * w2h + w3h * r1.x;
    aV10 += BFLO(v1u) * w2l + w3l * r1.y;
    aV11 += BFHI(v1u) * w2h + w3h * r1.y;
    aV20 += BFLO(v2u) * w2l + w3l * r1.z;
    aV21 += BFHI(v2u) * w2h + w3h * r1.z;
  }
  float2* sp = (float2*)(scalar + (size_t)n * 128) + lane;
  float2 s = *sp;
  s.x += aS0;
  s.y += aS1;
  *sp = s;
  float2* vp0 = (float2*)(vec + (size_t)n * 384) + lane;
  float2* vp1 = (float2*)(vec + (size_t)n * 384 + 128) + lane;
  float2* vp2 = (float2*)(vec + (size_t)n * 384 + 256) + lane;
  float2 v0 = *vp0, v1 = *vp1, v2 = *vp2;
  v0.x += aV00; v0.y += aV01;
  v1.x += aV10; v1.y += aV11;
  v2.x += aV20; v2.y += aV21;
  *vp0 = v0; *vp1 = v1; *vp2 = v2;
  uint* ob = (uint*)(vbout + (size_t)n * 384);
  ob[lane] = (uint)f2bf(v0.x) | ((uint)f2bf(v0.y) << 16);
  ob[lane + 64] = (uint)f2bf(v1.x) | ((uint)f2bf(v1.y) << 16);
  ob[lane + 128] = (uint)f2bf(v2.x) | ((uint)f2bf(v2.y) << 16);
}

// ---------------- bf16 MFMA GEMM: C = act(A[M,K] @ WT[N,K]^T + b) ----------------
template <bool SILU, bool HASB, bool OUTBF>
__global__ __launch_bounds__(256) void gemm_kernel(const ushort* __restrict__ A,
                                                   const ushort* __restrict__ WT,
                                                   const float* __restrict__ bias,
                                                   void* __restrict__ Cout, int M, int K, int Nn) {
  __shared__ ushort As[64 * 128];
  __shared__ ushort Bs[64 * 128];
  int tid = threadIdx.x;
  int m0 = blockIdx.x * 64, n0 = blockIdx.y * 64;
  int lane = tid & 63, w = tid >> 6, wr = w >> 1, wc = w & 1;
  f32x4 acc[2][2] = {};
  for (int k0 = 0; k0 < K; k0 += 128) {
    __syncthreads();
#pragma unroll
    for (int r = 0; r < 4; ++r) {
      int c = tid + r * 256;
      int row = c >> 4, col16 = c & 15;
      uint4 av = make_uint4(0, 0, 0, 0);
      if (m0 + row < M) av = *(const uint4*)(A + (size_t)(m0 + row) * K + k0 + col16 * 8);
      *(uint4*)(&As[row * 128 + ((col16 ^ (row & 7)) * 8)]) = av;
      uint4 bv = *(const uint4*)(WT + (size_t)(n0 + row) * K + k0 + col16 * 8);
      *(uint4*)(&Bs[row * 128 + ((col16 ^ (row & 7)) * 8)]) = bv;
    }
    __syncthreads();
#pragma unroll
    for (int ks = 0; ks < 4; ++ks) {
      int ch = ks * 4 + (lane >> 4);
      int ra0 = wr * 32 + (lane & 15), ra1 = ra0 + 16;
      int rb0 = wc * 32 + (lane & 15), rb1 = rb0 + 16;
      bf16x8 a0 = *(bf16x8*)&As[ra0 * 128 + ((ch ^ (ra0 & 7)) * 8)];
      bf16x8 a1 = *(bf16x8*)&As[ra1 * 128 + ((ch ^ (ra1 & 7)) * 8)];
      bf16x8 b0 = *(bf16x8*)&Bs[rb0 * 128 + ((ch ^ (rb0 & 7)) * 8)];
      bf16x8 b1 = *(bf16x8*)&Bs[rb1 * 128 + ((ch ^ (rb1 & 7)) * 8)];
      acc[0][0] = __builtin_amdgcn_mfma_f32_16x16x32_bf16(a0, b0, acc[0][0], 0, 0, 0);
      acc[0][1] = __builtin_amdgcn_mfma_f32_16x16x32_bf16(a0, b1, acc[0][1], 0, 0, 0);
      acc[1][0] = __builtin_amdgcn_mfma_f32_16x16x32_bf16(a1, b0, acc[1][0], 0, 0, 0);
      acc[1][1] = __builtin_amdgcn_mfma_f32_16x16x32_bf16(a1, b1, acc[1][1], 0, 0, 0);
    }
  }
  int cl = lane & 15, rq = lane >> 4;
#pragma unroll
  for (int ms = 0; ms < 2; ++ms)
#pragma unroll
    for (int ns = 0; ns < 2; ++ns) {
      int n = n0 + wc * 32 + ns * 16 + cl;
      float bv = HASB ? bias[n] : 0.0f;
#pragma unroll
      for (int j = 0; j < 4; ++j) {
        int m = m0 + wr * 32 + ms * 16 + rq * 4 + j;
        if (m >= M) continue;
        float v = acc[ms][ns][j] + bv;
        if (SILU) v = silu_f(v);
        if (OUTBF)
          ((ushort*)Cout)[(size_t)m * Nn + n] = f2bf(v);
        else
          ((float*)Cout)[(size_t)m * Nn + n] = v;
      }
    }
}

// ---------------- v_norm + concat(scalar, v_norm) -> bf16 ----------------
__global__ void vnorm_kernel(const float* __restrict__ uvvv, const float* __restrict__ scalar,
                             ushort* __restrict__ cat, int N) {
  int idx = blockIdx.x * 256 + threadIdx.x;
  if (idx >= N * 128) return;
  int n = idx >> 7, j = idx & 127;
  const float* b = uvvv + (size_t)n * 768;
  float v0 = b[128 + j], v1 = b[384 + j], v2 = b[640 + j];
  float vn = sqrtf(v0 * v0 + v1 * v1 + v2 * v2 + 1e-8f);
  cat[(size_t)n * 256 + j] = f2bf(scalar[idx]);
  cat[(size_t)n * 256 + 128 + j] = f2bf(vn);
}

// ---------------- update combine ----------------
__global__ void combine_kernel(const float* __restrict__ uvvv, const float* __restrict__ a,
                               float* __restrict__ scalar, ushort* __restrict__ sbf,
                               float* __restrict__ vec, ushort* __restrict__ vbf, int N) {
  int idx = blockIdx.x * 256 + threadIdx.x;
  if (idx >= N * 128) return;
  int n = idx >> 7, j = idx & 127;
  const float* b = uvvv + (size_t)n * 768;
  float u0 = b[j], w0 = b[128 + j];
  float u1 = b[256 + j], w1 = b[384 + j];
  float u2 = b[512 + j], w2 = b[640 + j];
  float dot = u0 * w0 + u1 * w1 + u2 * w2;
  const float* ab = a + (size_t)n * 384;
  float a1 = ab[j], a2 = ab[128 + j], a3 = ab[256 + j];
  float s = scalar[idx] + a1 + a2 * dot;
  scalar[idx] = s;
  sbf[idx] = f2bf(s);
  size_t vb = (size_t)n * 384 + j;
  float nv0 = vec[vb] + a3 * u0;
  float nv1 = vec[vb + 128] + a3 * u1;
  float nv2 = vec[vb + 256] + a3 * u2;
  vec[vb] = nv0;
  vec[vb + 128] = nv1;
  vec[vb + 256] = nv2;
  vbf[vb] = f2bf(nv0);
  vbf[vb + 128] = f2bf(nv1);
  vbf[vb + 256] = f2bf(nv2);
}

// ---------------- readout: e_atom dot + segment sum ----------------
__global__ void readout_kernel(const float* __restrict__ t3, const float* __restrict__ r_w2,
                               const float* __restrict__ r_b2, const int* __restrict__ bidx,
                               float* __restrict__ out, int N) {
  int lane = threadIdx.x & 63;
  int n = blockIdx.x * 4 + (threadIdx.x >> 6);
  if (n >= N) return;
  float v = t3[(size_t)n * 64 + lane] * r_w2[lane];
#pragma unroll
  for (int o = 32; o > 0; o >>= 1) v += __shfl_down(v, o);
  if (lane == 0) atomicAdd(&out[bidx[n]], v + r_b2[0]);
}

extern "C" void kernel_launch(void* const* d_in, const int* in_sizes, int n_in, void* d_out,
                              int out_size, void* d_ws, size_t ws_size, hipStream_t stream) {
  const int N = in_sizes[0];
  const int E = in_sizes[2] / 2;
  const int G = out_size;

  const int* z = (const int*)d_in[0];
  const float* pos = (const float*)d_in[1];
  const int* ei = (const int*)d_in[2];
  const float* shifts = (const float*)d_in[3];
  const int* bidx = (const int*)d_in[4];
  const float* emb = (const float*)d_in[5];
  const float* m_w1 = (const float*)d_in[6];
  const float* m_b1 = (const float*)d_in[7];
  const float* m_w2 = (const float*)d_in[8];
  const float* m_b2 = (const float*)d_in[9];
  const float* f_w = (const float*)d_in[10];
  const float* f_b = (const float*)d_in[11];
  const float* u_w = (const float*)d_in[12];
  const float* v_w = (const float*)d_in[13];
  const float* up_w1 = (const float*)d_in[14];
  const float* up_b1 = (const float*)d_in[15];
  const float* up_w2 = (const float*)d_in[16];
  const float* up_b2 = (const float*)d_in[17];
  const float* r_w1 = (const float*)d_in[18];
  const float* r_b1 = (const float*)d_in[19];
  const float* r_w2 = (const float*)d_in[20];
  const float* r_b2 = (const float*)d_in[21];
  float* out = (float*)d_out;

  float* w = (float*)d_ws;
  size_t off = 0;
  auto alloc = [&](size_t nfl) { float* p = w + off; off += (nfl + 3) & ~(size_t)3; return p; };
  ushort* tab = (ushort*)alloc((size_t)3 * TL * 192);     // bf16 table
  float* scalar = alloc((size_t)N * 128);                 // fp32 master
  ushort* sbf = (ushort*)alloc((size_t)N * 64);           // bf16 mirror of scalar
  float* vec = alloc((size_t)N * 384);                    // fp32 master vector
  ushort* mirA = (ushort*)alloc((size_t)N * 192);         // bf16 vector mirrors (ping/pong)
  ushort* mirB = (ushort*)alloc((size_t)N * 192);
  ushort* hn_bf = (ushort*)alloc((size_t)N * 192);        // message MLP output, bf16
  ushort* t1_bf = (ushort*)alloc((size_t)N * 64);         // [N,128] bf16
  ushort* cat_bf = (ushort*)alloc((size_t)N * 128);       // [N,256] bf16
  float* uvvv = alloc((size_t)N * 768);                   // [3N,256] fp32 (uv||vv)
  float* abuf = alloc((size_t)N * 384);                   // up2 output fp32
  float* t3 = alloc((size_t)N * 64);
  float* pkf = alloc((size_t)E * 8);
  ushort* wt = (ushort*)alloc((size_t)274432);            // packed transposed weights bf16
  int* counts = (int*)alloc((size_t)N);
  int* offs = (int*)alloc((size_t)N + 4);
  int* cursor = (int*)alloc((size_t)N);
  if (off * sizeof(float) > ws_size) return;

  hipMemsetAsync(counts, 0, (size_t)N * sizeof(int), stream);
  hipMemsetAsync(vec, 0, (size_t)N * 384 * sizeof(float), stream);
  hipMemsetAsync(mirA, 0, (size_t)N * 384 * sizeof(ushort), stream);
  hipMemsetAsync(out, 0, (size_t)G * sizeof(float), stream);

  emb_kernel<<<(N * 128 + 255) / 256, 256, 0, stream>>>(z, emb, scalar, sbf, N);
  wconv_kernel<<<(548864 + 255) / 256, 256, 0, stream>>>(m_w1, m_w2, u_w, v_w, up_w1, up_w2,
                                                         r_w1, wt);
  table_kernel<<<(3 * TL * 384 + 255) / 256, 256, 0, stream>>>(f_w, f_b, tab);
  count_kernel<<<(E + 255) / 256, 256, 0, stream>>>(pos, ei, shifts, counts, E);
  scan_kernel<<<1, 1024, 0, stream>>>(counts, offs, cursor, N);
  fill_kernel<<<(E + 255) / 256, 256, 0, stream>>>(pos, ei, shifts, cursor, (float4*)pkf, E);

  dim3 g1((N + 63) / 64, 2);        // [N,128]
  dim3 g2((N + 63) / 64, 6);        // [N,384]
  dim3 g3((3 * N + 63) / 64, 4);    // [3N,256]
  dim3 gr((N + 63) / 64, 1);        // [N,64]
  int ge = (N * 128 + 255) / 256;

  for (int l = 0; l < 3; l++) {
    ushort* mir_in = (l & 1) ? mirB : mirA;
    ushort* mir_out = (l & 1) ? mirA : mirB;
    const ushort* wl = wt + (size_t)l * 180224;
    gemm_kernel<true, true, true><<<g1, 256, 0, stream>>>(sbf, wl, m_b1 + l * 128, t1_bf, N, 128,
                                                          128);
    gemm_kernel<false, true, true><<<g2, 256, 0, stream>>>(t1_bf, wl + 16384, m_b2 + l * 384,
                                                           hn_bf, N, 128, 384);
    message_kernel<<<(N + 3) / 4, 256, 0, stream>>>(offs, (const float4*)pkf, (const uint*)hn_bf,
                                                    (const uint*)mir_in,
                                                    (const uint*)(tab + (size_t)l * TL * 384),
                                                    scalar, vec, mir_out, N);
    gemm_kernel<false, false, false><<<g3, 256, 0, stream>>>(mir_out, wl + 65536, nullptr, uvvv,
                                                             3 * N, 128, 256);
    vnorm_kernel<<<ge, 256, 0, stream>>>(uvvv, scalar, cat_bf, N);
    gemm_kernel<true, true, true><<<g1, 256, 0, stream>>>(cat_bf, wl + 98304, up_b1 + l * 128,
                                                          t1_bf, N, 256, 128);
    gemm_kernel<false, true, false><<<g2, 256, 0, stream>>>(t1_bf, wl + 131072, up_b2 + l * 384,
                                                            abuf, N, 128, 384);
    combine_kernel<<<ge, 256, 0, stream>>>(uvvv, abuf, scalar, sbf, vec, mir_out, N);
  }

  gemm_kernel<true, true, false><<<gr, 256, 0, stream>>>(sbf, wt + 540672, r_b1, t3, N, 128, 64);
  readout_kernel<<<(N + 3) / 4, 256, 0, stream>>>(t3, r_w2, r_b2, bidx, out, N);
}

// Round 3
// 525.674 us; speedup vs baseline: 2.0678x; 1.1926x over previous
//
#include <hip/hip_runtime.h>
#include <math.h>

#define CUTR 5.0f
#define TL 2048
#define NBASIS 32

typedef __attribute__((ext_vector_type(8))) short bf16x8;
typedef __attribute__((ext_vector_type(4))) float f32x4;

__device__ __forceinline__ float silu_f(float x) { return x / (1.0f + expf(-x)); }
__device__ __forceinline__ ushort f2bf(float x) {
  uint b = __float_as_uint(x);
  uint r = (b + 0x7FFFu + ((b >> 16) & 1u)) >> 16;
  return (ushort)r;
}
#define BFLO(u) __uint_as_float((u) << 16)
#define BFHI(u) __uint_as_float((u) & 0xFFFF0000u)

// ---------------- scalar init from embedding ----------------
__global__ void emb_kernel(const int* __restrict__ z, const float* __restrict__ emb,
                           float* __restrict__ scalar, ushort* __restrict__ sbf, int N) {
  int idx = blockIdx.x * 256 + threadIdx.x;
  if (idx >= N * 128) return;
  int n = idx >> 7, j = idx & 127;
  float v = emb[z[n] * 128 + j];
  scalar[idx] = v;
  sbf[idx] = f2bf(v);
}

// ---------------- weight convert + transpose to bf16 [N][K] ----------------
__global__ void wconv_kernel(const float* __restrict__ m_w1, const float* __restrict__ m_w2,
                             const float* __restrict__ u_w, const float* __restrict__ v_w,
                             const float* __restrict__ up_w1, const float* __restrict__ up_w2,
                             const float* __restrict__ r_w1, ushort* __restrict__ wt) {
  int idx = blockIdx.x * 256 + threadIdx.x;
  if (idx >= 548864) return;
  float v;
  if (idx >= 540672) {
    int t = idx - 540672;
    int n = t >> 7, k = t & 127;
    v = r_w1[k * 64 + n];
  } else {
    int l = idx / 180224, local = idx % 180224;
    if (local < 16384) {
      int n = local >> 7, k = local & 127;
      v = m_w1[l * 16384 + k * 128 + n];
    } else if (local < 65536) {
      int t = local - 16384;
      int n = t >> 7, k = t & 127;
      v = m_w2[l * 49152 + k * 384 + n];
    } else if (local < 98304) {
      int t = local - 65536;
      int n = t >> 7, k = t & 127;
      v = (n < 128) ? u_w[l * 16384 + k * 128 + n] : v_w[l * 16384 + k * 128 + (n - 128)];
    } else if (local < 131072) {
      int t = local - 98304;
      int n = t >> 8, k = t & 255;
      v = up_w1[l * 32768 + k * 128 + n];
    } else {
      int t = local - 131072;
      int n = t >> 7, k = t & 127;
      v = up_w2[l * 49152 + k * 384 + n];
    }
  }
  wt[idx] = f2bf(v);
}

// ---------------- radial filter table (bf16) ----------------
__global__ void table_kernel(const float* __restrict__ f_w, const float* __restrict__ f_b,
                             ushort* __restrict__ tab) {
  int idx = blockIdx.x * 256 + threadIdx.x;
  if (idx >= 3 * TL * 384) return;
  int j = idx % 384;
  int t = (idx / 384) % TL;
  int l = idx / (384 * TL);
  float len = (float)t * (CUTR / (float)(TL - 1));
  float s = len * (1.0f / CUTR);
  float g = 0.0f;
  if (s < 1.0f) g = expf(1.0f - 1.0f / (1.0f - s * s));
  const float gamma = (31.0f / 5.0f) * (31.0f / 5.0f);
  float acc = 0.0f;
  const float* fw = f_w + (size_t)l * NBASIS * 384 + j;
#pragma unroll
  for (int k = 0; k < NBASIS; k++) {
    float c = 5.0f * (float)k / 31.0f;
    float d = len - c;
    acc += expf(-gamma * d * d) * fw[k * 384];
  }
  tab[idx] = f2bf(g * (g * acc + f_b[l * 384 + j]));
}

// ---------------- CSR build over ACTIVE edges (len < CUT) ----------------
__global__ void count_kernel(const float* __restrict__ pos, const int* __restrict__ ei,
                             const float* __restrict__ shifts, int* __restrict__ counts, int E) {
  int e = blockIdx.x * 256 + threadIdx.x;
  if (e >= E) return;
  int r = ei[e], c = ei[E + e];
  float dx = pos[c * 3 + 0] - pos[r * 3 + 0] + shifts[e * 3 + 0];
  float dy = pos[c * 3 + 1] - pos[r * 3 + 1] + shifts[e * 3 + 1];
  float dz = pos[c * 3 + 2] - pos[r * 3 + 2] + shifts[e * 3 + 2];
  float len = sqrtf(dx * dx + dy * dy + dz * dz + 1e-12f);
  if (len < CUTR) atomicAdd(&counts[r], 1);
}

__global__ __launch_bounds__(1024) void scan_kernel(const int* __restrict__ counts,
                                                    int* __restrict__ offs,
                                                    int* __restrict__ cursor, int N) {
  __shared__ int sm[1024];
  int tid = threadIdx.x;
  int CH = (N + 1023) / 1024;
  int base = tid * CH;
  int sum = 0;
  for (int i = 0; i < CH; i++) sum += (base + i < N) ? counts[base + i] : 0;
  sm[tid] = sum;
  __syncthreads();
  for (int o = 1; o < 1024; o <<= 1) {
    int v = (tid >= o) ? sm[tid - o] : 0;
    __syncthreads();
    sm[tid] += v;
    __syncthreads();
  }
  int run = sm[tid] - sum;
  for (int i = 0; i < CH; i++) {
    if (base + i < N) {
      offs[base + i] = run;
      cursor[base + i] = run;
      run += counts[base + i];
    }
  }
  if (tid == 1023) offs[N] = sm[1023];
}

__global__ void fill_kernel(const float* __restrict__ pos, const int* __restrict__ ei,
                            const float* __restrict__ shifts, int* __restrict__ cursor,
                            float4* __restrict__ pk, int E) {
  int e = blockIdx.x * 256 + threadIdx.x;
  if (e >= E) return;
  int r = ei[e], c = ei[E + e];
  float dx = pos[c * 3 + 0] - pos[r * 3 + 0] + shifts[e * 3 + 0];
  float dy = pos[c * 3 + 1] - pos[r * 3 + 1] + shifts[e * 3 + 1];
  float dz = pos[c * 3 + 2] - pos[r * 3 + 2] + shifts[e * 3 + 2];
  float len = sqrtf(dx * dx + dy * dy + dz * dz + 1e-12f);
  if (len >= CUTR) return;
  float inv = 1.0f / len;
  float x = len * ((float)(TL - 1) / CUTR);
  int ib = (int)x;
  if (ib > TL - 2) ib = TL - 2;
  float fr = x - (float)ib;
  int p = atomicAdd(&cursor[r], 1);
  pk[2 * p] = make_float4(__int_as_float(c), fr, __int_as_float(ib), 0.0f);
  pk[2 * p + 1] = make_float4(dx * inv, dy * inv, dz * inv, 0.0f);
}

// ---------------- fused message: one wave per destination node, bf16 gathers ----------------
__global__ __launch_bounds__(256) void message_kernel(
    const int* __restrict__ offs, const float4* __restrict__ pk, const uint* __restrict__ hn,
    const uint* __restrict__ vbin, const uint* __restrict__ tab, float* __restrict__ scalar,
    ushort* __restrict__ sbf, float* __restrict__ vec, ushort* __restrict__ vbout, int N) {
  int lane = threadIdx.x & 63;
  int n = blockIdx.x * 4 + (threadIdx.x >> 6);
  if (n >= N) return;
  int p0 = offs[n], p1 = offs[n + 1];
  float aS0 = 0.f, aS1 = 0.f;
  float aV00 = 0.f, aV01 = 0.f, aV10 = 0.f, aV11 = 0.f, aV20 = 0.f, aV21 = 0.f;
  for (int p = p0; p < p1; ++p) {
    float4 r0 = pk[2 * p];
    float4 r1 = pk[2 * p + 1];
    int col = __float_as_int(r0.x);
    float fr = r0.y;
    int ib = __float_as_int(r0.z);
    const uint* hb = hn + (size_t)col * 192;
    const uint* vb = vbin + (size_t)col * 192;
    const uint* tb = tab + (size_t)ib * 192;
    uint h1u = hb[lane], h2u = hb[lane + 64], h3u = hb[lane + 128];
    uint v0u = vb[lane], v1u = vb[lane + 64], v2u = vb[lane + 128];
    uint ta0 = tb[lane], tb0 = tb[lane + 64], tc0 = tb[lane + 128];
    uint ta1 = tb[lane + 192], tb1 = tb[lane + 256], tc1 = tb[lane + 320];
    float f1l = BFLO(ta0) + fr * (BFLO(ta1) - BFLO(ta0));
    float f1h = BFHI(ta0) + fr * (BFHI(ta1) - BFHI(ta0));
    float f2l = BFLO(tb0) + fr * (BFLO(tb1) - BFLO(tb0));
    float f2h = BFHI(tb0) + fr * (BFHI(tb1) - BFHI(tb0));
    float f3l = BFLO(tc0) + fr * (BFLO(tc1) - BFLO(tc0));
    float f3h = BFHI(tc0) + fr * (BFHI(tc1) - BFHI(tc0));
    float w1l = BFLO(h1u) * f1l, w1h = BFHI(h1u) * f1h;
    float w2l = BFLO(h2u) * f2l, w2h = BFHI(h2u) * f2h;
    float w3l = BFLO(h3u) * f3l, w3h = BFHI(h3u) * f3h;
    aS0 += w1l;
    aS1 += w1h;
    aV00 += BFLO(v0u) * w2l + w3l * r1.x;
    aV01 += BFHI(v0u) * w2h + w3h * r1.x;
    aV10 += BFLO(v1u) * w2l + w3l * r1.y;
    aV11 += BFHI(v1u) * w2h + w3h * r1.y;
    aV20 += BFLO(v2u) * w2l + w3l * r1.z;
    aV21 += BFHI(v2u) * w2h + w3h * r1.z;
  }
  float2* sp = (float2*)(scalar + (size_t)n * 128) + lane;
  float2 s = *sp;
  s.x += aS0;
  s.y += aS1;
  *sp = s;
  ((uint*)(sbf + (size_t)n * 128))[lane] = (uint)f2bf(s.x) | ((uint)f2bf(s.y) << 16);
  float2* vp0 = (float2*)(vec + (size_t)n * 384) + lane;
  float2* vp1 = (float2*)(vec + (size_t)n * 384 + 128) + lane;
  float2* vp2 = (float2*)(vec + (size_t)n * 384 + 256) + lane;
  float2 v0 = *vp0, v1 = *vp1, v2 = *vp2;
  v0.x += aV00; v0.y += aV01;
  v1.x += aV10; v1.y += aV11;
  v2.x += aV20; v2.y += aV21;
  *vp0 = v0; *vp1 = v1; *vp2 = v2;
  uint* ob = (uint*)(vbout + (size_t)n * 384);
  ob[lane] = (uint)f2bf(v0.x) | ((uint)f2bf(v0.y) << 16);
  ob[lane + 64] = (uint)f2bf(v1.x) | ((uint)f2bf(v1.y) << 16);
  ob[lane + 128] = (uint)f2bf(v2.x) | ((uint)f2bf(v2.y) << 16);
}

// ---------------- bf16 MFMA GEMM: C = act(A[M,K] @ WT[N,K]^T + b) ----------------
template <bool SILU, bool HASB, bool OUTBF>
__global__ __launch_bounds__(256) void gemm_kernel(const ushort* __restrict__ A,
                                                   const ushort* __restrict__ WT,
                                                   const float* __restrict__ bias,
                                                   void* __restrict__ Cout, int M, int K, int Nn) {
  __shared__ ushort As[64 * 128];
  __shared__ ushort Bs[64 * 128];
  int tid = threadIdx.x;
  int m0 = blockIdx.x * 64, n0 = blockIdx.y * 64;
  int lane = tid & 63, w = tid >> 6, wr = w >> 1, wc = w & 1;
  f32x4 acc[2][2] = {};
  for (int k0 = 0; k0 < K; k0 += 128) {
    __syncthreads();
#pragma unroll
    for (int r = 0; r < 4; ++r) {
      int c = tid + r * 256;
      int row = c >> 4, col16 = c & 15;
      uint4 av = make_uint4(0, 0, 0, 0);
      if (m0 + row < M) av = *(const uint4*)(A + (size_t)(m0 + row) * K + k0 + col16 * 8);
      *(uint4*)(&As[row * 128 + ((col16 ^ (row & 7)) * 8)]) = av;
      uint4 bv = *(const uint4*)(WT + (size_t)(n0 + row) * K + k0 + col16 * 8);
      *(uint4*)(&Bs[row * 128 + ((col16 ^ (row & 7)) * 8)]) = bv;
    }
    __syncthreads();
#pragma unroll
    for (int ks = 0; ks < 4; ++ks) {
      int ch = ks * 4 + (lane >> 4);
      int ra0 = wr * 32 + (lane & 15), ra1 = ra0 + 16;
      int rb0 = wc * 32 + (lane & 15), rb1 = rb0 + 16;
      bf16x8 a0 = *(bf16x8*)&As[ra0 * 128 + ((ch ^ (ra0 & 7)) * 8)];
      bf16x8 a1 = *(bf16x8*)&As[ra1 * 128 + ((ch ^ (ra1 & 7)) * 8)];
      bf16x8 b0 = *(bf16x8*)&Bs[rb0 * 128 + ((ch ^ (rb0 & 7)) * 8)];
      bf16x8 b1 = *(bf16x8*)&Bs[rb1 * 128 + ((ch ^ (rb1 & 7)) * 8)];
      acc[0][0] = __builtin_amdgcn_mfma_f32_16x16x32_bf16(a0, b0, acc[0][0], 0, 0, 0);
      acc[0][1] = __builtin_amdgcn_mfma_f32_16x16x32_bf16(a0, b1, acc[0][1], 0, 0, 0);
      acc[1][0] = __builtin_amdgcn_mfma_f32_16x16x32_bf16(a1, b0, acc[1][0], 0, 0, 0);
      acc[1][1] = __builtin_amdgcn_mfma_f32_16x16x32_bf16(a1, b1, acc[1][1], 0, 0, 0);
    }
  }
  int cl = lane & 15, rq = lane >> 4;
#pragma unroll
  for (int ms = 0; ms < 2; ++ms)
#pragma unroll
    for (int ns = 0; ns < 2; ++ns) {
      int n = n0 + wc * 32 + ns * 16 + cl;
      float bv = HASB ? bias[n] : 0.0f;
#pragma unroll
      for (int j = 0; j < 4; ++j) {
        int m = m0 + wr * 32 + ms * 16 + rq * 4 + j;
        if (m >= M) continue;
        float v = acc[ms][ns][j] + bv;
        if (SILU) v = silu_f(v);
        if (OUTBF)
          ((ushort*)Cout)[(size_t)m * Nn + n] = f2bf(v);
        else
          ((float*)Cout)[(size_t)m * Nn + n] = v;
      }
    }
}

// ---------------- v_norm + concat(scalar_bf, v_norm) -> bf16 ----------------
__global__ void vnorm_kernel(const float* __restrict__ uvvv, const ushort* __restrict__ sbf,
                             ushort* __restrict__ cat, int N) {
  int idx = blockIdx.x * 256 + threadIdx.x;
  if (idx >= N * 128) return;
  int n = idx >> 7, j = idx & 127;
  const float* b = uvvv + (size_t)n * 768;
  float v0 = b[128 + j], v1 = b[384 + j], v2 = b[640 + j];
  float vn = sqrtf(v0 * v0 + v1 * v1 + v2 * v2 + 1e-8f);
  cat[(size_t)n * 256 + j] = sbf[idx];
  cat[(size_t)n * 256 + 128 + j] = f2bf(vn);
}

// ---------------- update combine ----------------
__global__ void combine_kernel(const float* __restrict__ uvvv, const float* __restrict__ a,
                               float* __restrict__ scalar, ushort* __restrict__ sbf,
                               float* __restrict__ vec, ushort* __restrict__ vbf, int N) {
  int idx = blockIdx.x * 256 + threadIdx.x;
  if (idx >= N * 128) return;
  int n = idx >> 7, j = idx & 127;
  const float* b = uvvv + (size_t)n * 768;
  float u0 = b[j], w0 = b[128 + j];
  float u1 = b[256 + j], w1 = b[384 + j];
  float u2 = b[512 + j], w2 = b[640 + j];
  float dot = u0 * w0 + u1 * w1 + u2 * w2;
  const float* ab = a + (size_t)n * 384;
  float a1 = ab[j], a2 = ab[128 + j], a3 = ab[256 + j];
  float s = scalar[idx] + a1 + a2 * dot;
  scalar[idx] = s;
  sbf[idx] = f2bf(s);
  size_t vb = (size_t)n * 384 + j;
  float nv0 = vec[vb] + a3 * u0;
  float nv1 = vec[vb + 128] + a3 * u1;
  float nv2 = vec[vb + 256] + a3 * u2;
  vec[vb] = nv0;
  vec[vb + 128] = nv1;
  vec[vb + 256] = nv2;
  vbf[vb] = f2bf(nv0);
  vbf[vb + 128] = f2bf(nv1);
  vbf[vb + 256] = f2bf(nv2);
}

// ---------------- readout: grid-stride, LDS per-graph partials, 8 atomics/block ----------------
__global__ __launch_bounds__(256) void readout_kernel(const float* __restrict__ t3,
                                                      const float* __restrict__ r_w2,
                                                      const float* __restrict__ r_b2,
                                                      const int* __restrict__ bidx,
                                                      float* __restrict__ out, int N, int G) {
  __shared__ float sm[64];
  int tid = threadIdx.x;
  if (tid < 64) sm[tid] = 0.f;
  __syncthreads();
  int lane = tid & 63, wid = tid >> 6;
  float wv = r_w2[lane];
  float rb2 = r_b2[0];
  bool ldsG = (G <= 64);
  for (int n = blockIdx.x * 4 + wid; n < N; n += gridDim.x * 4) {
    float v = t3[(size_t)n * 64 + lane] * wv;
#pragma unroll
    for (int o = 32; o > 0; o >>= 1) v += __shfl_down(v, o);
    if (lane == 0) {
      int g = bidx[n];
      if (ldsG)
        atomicAdd(&sm[g], v + rb2);
      else
        atomicAdd(&out[g], v + rb2);
    }
  }
  __syncthreads();
  if (ldsG && tid < G) atomicAdd(&out[tid], sm[tid]);
}

extern "C" void kernel_launch(void* const* d_in, const int* in_sizes, int n_in, void* d_out,
                              int out_size, void* d_ws, size_t ws_size, hipStream_t stream) {
  const int N = in_sizes[0];
  const int E = in_sizes[2] / 2;
  const int G = out_size;

  const int* z = (const int*)d_in[0];
  const float* pos = (const float*)d_in[1];
  const int* ei = (const int*)d_in[2];
  const float* shifts = (const float*)d_in[3];
  const int* bidx = (const int*)d_in[4];
  const float* emb = (const float*)d_in[5];
  const float* m_w1 = (const float*)d_in[6];
  const float* m_b1 = (const float*)d_in[7];
  const float* m_w2 = (const float*)d_in[8];
  const float* m_b2 = (const float*)d_in[9];
  const float* f_w = (const float*)d_in[10];
  const float* f_b = (const float*)d_in[11];
  const float* u_w = (const float*)d_in[12];
  const float* v_w = (const float*)d_in[13];
  const float* up_w1 = (const float*)d_in[14];
  const float* up_b1 = (const float*)d_in[15];
  const float* up_w2 = (const float*)d_in[16];
  const float* up_b2 = (const float*)d_in[17];
  const float* r_w1 = (const float*)d_in[18];
  const float* r_b1 = (const float*)d_in[19];
  const float* r_w2 = (const float*)d_in[20];
  const float* r_b2 = (const float*)d_in[21];
  float* out = (float*)d_out;

  float* w = (float*)d_ws;
  size_t off = 0;
  auto alloc = [&](size_t nfl) { float* p = w + off; off += (nfl + 3) & ~(size_t)3; return p; };
  ushort* tab = (ushort*)alloc((size_t)3 * TL * 192);
  float* scalar = alloc((size_t)N * 128);
  ushort* sbf = (ushort*)alloc((size_t)N * 64);
  float* vec = alloc((size_t)N * 384);
  ushort* mirA = (ushort*)alloc((size_t)N * 192);
  ushort* mirB = (ushort*)alloc((size_t)N * 192);
  ushort* hn_bf = (ushort*)alloc((size_t)N * 192);
  ushort* t1_bf = (ushort*)alloc((size_t)N * 64);
  ushort* cat_bf = (ushort*)alloc((size_t)N * 128);
  float* uvvv = alloc((size_t)N * 768);
  float* abuf = alloc((size_t)N * 384);
  float* t3 = alloc((size_t)N * 64);
  float* pkf = alloc((size_t)E * 8);
  ushort* wt = (ushort*)alloc((size_t)274432);
  int* counts = (int*)alloc((size_t)N);
  int* offs = (int*)alloc((size_t)N + 4);
  int* cursor = (int*)alloc((size_t)N);
  if (off * sizeof(float) > ws_size) return;

  hipMemsetAsync(counts, 0, (size_t)N * sizeof(int), stream);
  hipMemsetAsync(vec, 0, (size_t)N * 384 * sizeof(float), stream);
  hipMemsetAsync(mirA, 0, (size_t)N * 384 * sizeof(ushort), stream);
  hipMemsetAsync(out, 0, (size_t)G * sizeof(float), stream);

  emb_kernel<<<(N * 128 + 255) / 256, 256, 0, stream>>>(z, emb, scalar, sbf, N);
  wconv_kernel<<<(548864 + 255) / 256, 256, 0, stream>>>(m_w1, m_w2, u_w, v_w, up_w1, up_w2,
                                                         r_w1, wt);
  table_kernel<<<(3 * TL * 384 + 255) / 256, 256, 0, stream>>>(f_w, f_b, tab);
  count_kernel<<<(E + 255) / 256, 256, 0, stream>>>(pos, ei, shifts, counts, E);
  scan_kernel<<<1, 1024, 0, stream>>>(counts, offs, cursor, N);
  fill_kernel<<<(E + 255) / 256, 256, 0, stream>>>(pos, ei, shifts, cursor, (float4*)pkf, E);

  dim3 g1((N + 63) / 64, 2);
  dim3 g2((N + 63) / 64, 6);
  dim3 g3((3 * N + 63) / 64, 4);
  dim3 gr((N + 63) / 64, 1);
  int ge = (N * 128 + 255) / 256;

  for (int l = 0; l < 3; l++) {
    ushort* mir_in = (l & 1) ? mirB : mirA;
    ushort* mir_out = (l & 1) ? mirA : mirB;
    const ushort* wl = wt + (size_t)l * 180224;
    gemm_kernel<true, true, true><<<g1, 256, 0, stream>>>(sbf, wl, m_b1 + l * 128, t1_bf, N, 128,
                                                          128);
    gemm_kernel<false, true, true><<<g2, 256, 0, stream>>>(t1_bf, wl + 16384, m_b2 + l * 384,
                                                           hn_bf, N, 128, 384);
    message_kernel<<<(N + 3) / 4, 256, 0, stream>>>(offs, (const float4*)pkf, (const uint*)hn_bf,
                                                    (const uint*)mir_in,
                                                    (const uint*)(tab + (size_t)l * TL * 384),
                                                    scalar, sbf, vec, mir_out, N);
    gemm_kernel<false, false, false><<<g3, 256, 0, stream>>>(mir_out, wl + 65536, nullptr, uvvv,
                                                             3 * N, 128, 256);
    vnorm_kernel<<<ge, 256, 0, stream>>>(uvvv, sbf, cat_bf, N);
    gemm_kernel<true, true, true><<<g1, 256, 0, stream>>>(cat_bf, wl + 98304, up_b1 + l * 128,
                                                          t1_bf, N, 256, 128);
    gemm_kernel<false, true, false><<<g2, 256, 0, stream>>>(t1_bf, wl + 131072, up_b2 + l * 384,
                                                            abuf, N, 128, 384);
    combine_kernel<<<ge, 256, 0, stream>>>(uvvv, abuf, scalar, sbf, vec, mir_out, N);
  }

  gemm_kernel<true, true, false><<<gr, 256, 0, stream>>>(sbf, wt + 540672, r_b1, t3, N, 128, 64);
  readout_kernel<<<64, 256, 0, stream>>>(t3, r_w2, r_b2, bidx, out, N, G);
}

// Round 4
// 495.763 us; speedup vs baseline: 2.1926x; 1.0603x over previous
//
#include <hip/hip_runtime.h>
#include <math.h>

#define CUTR 5.0f
#define TL 2048
#define NBASIS 32

typedef __attribute__((ext_vector_type(8))) short bf16x8;
typedef __attribute__((ext_vector_type(4))) float f32x4;

__device__ __forceinline__ float silu_f(float x) { return x / (1.0f + expf(-x)); }
__device__ __forceinline__ ushort f2bf(float x) {
  uint b = __float_as_uint(x);
  uint r = (b + 0x7FFFu + ((b >> 16) & 1u)) >> 16;
  return (ushort)r;
}
#define BFLO(u) __uint_as_float((u) << 16)
#define BFHI(u) __uint_as_float((u) & 0xFFFF0000u)

// ---------------- scalar init from embedding ----------------
__global__ void emb_kernel(const int* __restrict__ z, const float* __restrict__ emb,
                           float* __restrict__ scalar, ushort* __restrict__ sbf, int N) {
  int idx = blockIdx.x * 256 + threadIdx.x;
  if (idx >= N * 128) return;
  int n = idx >> 7, j = idx & 127;
  float v = emb[z[n] * 128 + j];
  scalar[idx] = v;
  sbf[idx] = f2bf(v);
}

// ---------------- weight convert + transpose to bf16 [N][K] ----------------
__global__ void wconv_kernel(const float* __restrict__ m_w1, const float* __restrict__ m_w2,
                             const float* __restrict__ u_w, const float* __restrict__ v_w,
                             const float* __restrict__ up_w1, const float* __restrict__ up_w2,
                             const float* __restrict__ r_w1, ushort* __restrict__ wt) {
  int idx = blockIdx.x * 256 + threadIdx.x;
  if (idx >= 548864) return;
  float v;
  if (idx >= 540672) {
    int t = idx - 540672;
    int n = t >> 7, k = t & 127;
    v = r_w1[k * 64 + n];
  } else {
    int l = idx / 180224, local = idx % 180224;
    if (local < 16384) {
      int n = local >> 7, k = local & 127;
      v = m_w1[l * 16384 + k * 128 + n];
    } else if (local < 65536) {
      int t = local - 16384;
      int n = t >> 7, k = t & 127;
      v = m_w2[l * 49152 + k * 384 + n];
    } else if (local < 98304) {
      int t = local - 65536;
      int n = t >> 7, k = t & 127;
      v = (n < 128) ? u_w[l * 16384 + k * 128 + n] : v_w[l * 16384 + k * 128 + (n - 128)];
    } else if (local < 131072) {
      int t = local - 98304;
      int n = t >> 8, k = t & 255;
      v = up_w1[l * 32768 + k * 128 + n];
    } else {
      int t = local - 131072;
      int n = t >> 7, k = t & 127;
      v = up_w2[l * 49152 + k * 384 + n];
    }
  }
  wt[idx] = f2bf(v);
}

// ---------------- radial filter table (bf16) ----------------
__global__ void table_kernel(const float* __restrict__ f_w, const float* __restrict__ f_b,
                             ushort* __restrict__ tab) {
  int idx = blockIdx.x * 256 + threadIdx.x;
  if (idx >= 3 * TL * 384) return;
  int j = idx % 384;
  int t = (idx / 384) % TL;
  int l = idx / (384 * TL);
  float len = (float)t * (CUTR / (float)(TL - 1));
  float s = len * (1.0f / CUTR);
  float g = 0.0f;
  if (s < 1.0f) g = expf(1.0f - 1.0f / (1.0f - s * s));
  const float gamma = (31.0f / 5.0f) * (31.0f / 5.0f);
  float acc = 0.0f;
  const float* fw = f_w + (size_t)l * NBASIS * 384 + j;
#pragma unroll
  for (int k = 0; k < NBASIS; k++) {
    float c = 5.0f * (float)k / 31.0f;
    float d = len - c;
    acc += expf(-gamma * d * d) * fw[k * 384];
  }
  tab[idx] = f2bf(g * (g * acc + f_b[l * 384 + j]));
}

// ---------------- CSR build over ACTIVE edges (len < CUT) ----------------
__global__ void count_kernel(const float* __restrict__ pos, const int* __restrict__ ei,
                             const float* __restrict__ shifts, int* __restrict__ counts, int E) {
  int e = blockIdx.x * 256 + threadIdx.x;
  if (e >= E) return;
  int r = ei[e], c = ei[E + e];
  float dx = pos[c * 3 + 0] - pos[r * 3 + 0] + shifts[e * 3 + 0];
  float dy = pos[c * 3 + 1] - pos[r * 3 + 1] + shifts[e * 3 + 1];
  float dz = pos[c * 3 + 2] - pos[r * 3 + 2] + shifts[e * 3 + 2];
  float len = sqrtf(dx * dx + dy * dy + dz * dz + 1e-12f);
  if (len < CUTR) atomicAdd(&counts[r], 1);
}

__global__ __launch_bounds__(1024) void scan_kernel(const int* __restrict__ counts,
                                                    int* __restrict__ offs,
                                                    int* __restrict__ cursor, int N) {
  __shared__ int sm[1024];
  int tid = threadIdx.x;
  int CH = (N + 1023) / 1024;
  int base = tid * CH;
  int sum = 0;
  for (int i = 0; i < CH; i++) sum += (base + i < N) ? counts[base + i] : 0;
  sm[tid] = sum;
  __syncthreads();
  for (int o = 1; o < 1024; o <<= 1) {
    int v = (tid >= o) ? sm[tid - o] : 0;
    __syncthreads();
    sm[tid] += v;
    __syncthreads();
  }
  int run = sm[tid] - sum;
  for (int i = 0; i < CH; i++) {
    if (base + i < N) {
      offs[base + i] = run;
      cursor[base + i] = run;
      run += counts[base + i];
    }
  }
  if (tid == 1023) offs[N] = sm[1023];
}

__global__ void fill_kernel(const float* __restrict__ pos, const int* __restrict__ ei,
                            const float* __restrict__ shifts, int* __restrict__ cursor,
                            float4* __restrict__ pk, int E) {
  int e = blockIdx.x * 256 + threadIdx.x;
  if (e >= E) return;
  int r = ei[e], c = ei[E + e];
  float dx = pos[c * 3 + 0] - pos[r * 3 + 0] + shifts[e * 3 + 0];
  float dy = pos[c * 3 + 1] - pos[r * 3 + 1] + shifts[e * 3 + 1];
  float dz = pos[c * 3 + 2] - pos[r * 3 + 2] + shifts[e * 3 + 2];
  float len = sqrtf(dx * dx + dy * dy + dz * dz + 1e-12f);
  if (len >= CUTR) return;
  float inv = 1.0f / len;
  float x = len * ((float)(TL - 1) / CUTR);
  int ib = (int)x;
  if (ib > TL - 2) ib = TL - 2;
  float fr = x - (float)ib;
  int p = atomicAdd(&cursor[r], 1);
  pk[2 * p] = make_float4(__int_as_float(c), fr, __int_as_float(ib), 0.0f);
  pk[2 * p + 1] = make_float4(dx * inv, dy * inv, dz * inv, 0.0f);
}

// ---------------- fused message: 2 waves per node, 2-edge unroll ----------------
__global__ __launch_bounds__(256) void message_kernel(
    const int* __restrict__ offs, const float4* __restrict__ pk, const uint* __restrict__ hn,
    const uint* __restrict__ vbin, const uint* __restrict__ tab, float* __restrict__ scalar,
    ushort* __restrict__ sbf, float* __restrict__ vec, ushort* __restrict__ vbout, int N) {
  __shared__ float red[2][64][8];
  int tid = threadIdx.x;
  int lane = tid & 63;
  int w = tid >> 6, slot = w >> 1, half = w & 1;
  int n = blockIdx.x * 2 + slot;
  bool valid = (n < N);
  int p0 = 0, p1 = 0;
  if (valid) {
    p0 = offs[n];
    p1 = offs[n + 1];
  }
  float aS0 = 0.f, aS1 = 0.f;
  float aV00 = 0.f, aV01 = 0.f, aV10 = 0.f, aV11 = 0.f, aV20 = 0.f, aV21 = 0.f;
  for (int p = p0 + half; p < p1; p += 4) {
    // --- edge A ---
    float4 rA0 = pk[2 * p];
    float4 rA1 = pk[2 * p + 1];
    int colA = __float_as_int(rA0.x);
    float frA = rA0.y;
    int ibA = __float_as_int(rA0.z);
    const uint* hbA = hn + (size_t)colA * 192;
    const uint* vbA = vbin + (size_t)colA * 192;
    const uint* tbA = tab + (size_t)ibA * 192;
    uint hA1 = hbA[lane], hA2 = hbA[lane + 64], hA3 = hbA[lane + 128];
    uint vA0 = vbA[lane], vA1 = vbA[lane + 64], vA2 = vbA[lane + 128];
    uint taA0 = tbA[lane], tbA0 = tbA[lane + 64], tcA0 = tbA[lane + 128];
    uint taA1 = tbA[lane + 192], tbA1 = tbA[lane + 256], tcA1 = tbA[lane + 320];
    // --- edge B (uniform branch) ---
    int pB = p + 2;
    bool hasB = pB < p1;
    float4 rB0, rB1;
    uint hB1, hB2, hB3, vB0, vB1, vB2, taB0, tbB0, tcB0, taB1, tbB1, tcB1;
    if (hasB) {
      rB0 = pk[2 * pB];
      rB1 = pk[2 * pB + 1];
      int colB = __float_as_int(rB0.x);
      int ibB = __float_as_int(rB0.z);
      const uint* hbB = hn + (size_t)colB * 192;
      const uint* vbB = vbin + (size_t)colB * 192;
      const uint* tbB = tab + (size_t)ibB * 192;
      hB1 = hbB[lane]; hB2 = hbB[lane + 64]; hB3 = hbB[lane + 128];
      vB0 = vbB[lane]; vB1 = vbB[lane + 64]; vB2 = vbB[lane + 128];
      taB0 = tbB[lane]; tbB0 = tbB[lane + 64]; tcB0 = tbB[lane + 128];
      taB1 = tbB[lane + 192]; tbB1 = tbB[lane + 256]; tcB1 = tbB[lane + 320];
    }
    // --- compute A ---
    {
      float fr = frA;
      float f1l = BFLO(taA0) + fr * (BFLO(taA1) - BFLO(taA0));
      float f1h = BFHI(taA0) + fr * (BFHI(taA1) - BFHI(taA0));
      float f2l = BFLO(tbA0) + fr * (BFLO(tbA1) - BFLO(tbA0));
      float f2h = BFHI(tbA0) + fr * (BFHI(tbA1) - BFHI(tbA0));
      float f3l = BFLO(tcA0) + fr * (BFLO(tcA1) - BFLO(tcA0));
      float f3h = BFHI(tcA0) + fr * (BFHI(tcA1) - BFHI(tcA0));
      float w1l = BFLO(hA1) * f1l, w1h = BFHI(hA1) * f1h;
      float w2l = BFLO(hA2) * f2l, w2h = BFHI(hA2) * f2h;
      float w3l = BFLO(hA3) * f3l, w3h = BFHI(hA3) * f3h;
      aS0 += w1l;
      aS1 += w1h;
      aV00 += BFLO(vA0) * w2l + w3l * rA1.x;
      aV01 += BFHI(vA0) * w2h + w3h * rA1.x;
      aV10 += BFLO(vA1) * w2l + w3l * rA1.y;
      aV11 += BFHI(vA1) * w2h + w3h * rA1.y;
      aV20 += BFLO(vA2) * w2l + w3l * rA1.z;
      aV21 += BFHI(vA2) * w2h + w3h * rA1.z;
    }
    // --- compute B ---
    if (hasB) {
      float fr = rB0.y;
      float f1l = BFLO(taB0) + fr * (BFLO(taB1) - BFLO(taB0));
      float f1h = BFHI(taB0) + fr * (BFHI(taB1) - BFHI(taB0));
      float f2l = BFLO(tbB0) + fr * (BFLO(tbB1) - BFLO(tbB0));
      float f2h = BFHI(tbB0) + fr * (BFHI(tbB1) - BFHI(tbB0));
      float f3l = BFLO(tcB0) + fr * (BFLO(tcB1) - BFLO(tcB0));
      float f3h = BFHI(tcB0) + fr * (BFHI(tcB1) - BFHI(tcB0));
      float w1l = BFLO(hB1) * f1l, w1h = BFHI(hB1) * f1h;
      float w2l = BFLO(hB2) * f2l, w2h = BFHI(hB2) * f2h;
      float w3l = BFLO(hB3) * f3l, w3h = BFHI(hB3) * f3h;
      aS0 += w1l;
      aS1 += w1h;
      aV00 += BFLO(vB0) * w2l + w3l * rB1.x;
      aV01 += BFHI(vB0) * w2h + w3h * rB1.x;
      aV10 += BFLO(vB1) * w2l + w3l * rB1.y;
      aV11 += BFHI(vB1) * w2h + w3h * rB1.y;
      aV20 += BFLO(vB2) * w2l + w3l * rB1.z;
      aV21 += BFHI(vB2) * w2h + w3h * rB1.z;
    }
  }
  if (half == 1) {
    float* r = &red[slot][lane][0];
    r[0] = aS0; r[1] = aS1;
    r[2] = aV00; r[3] = aV01;
    r[4] = aV10; r[5] = aV11;
    r[6] = aV20; r[7] = aV21;
  }
  __syncthreads();
  if (half == 0 && valid) {
    const float* r = &red[slot][lane][0];
    aS0 += r[0]; aS1 += r[1];
    aV00 += r[2]; aV01 += r[3];
    aV10 += r[4]; aV11 += r[5];
    aV20 += r[6]; aV21 += r[7];
    float2* sp = (float2*)(scalar + (size_t)n * 128) + lane;
    float2 s = *sp;
    s.x += aS0;
    s.y += aS1;
    *sp = s;
    ((uint*)(sbf + (size_t)n * 128))[lane] = (uint)f2bf(s.x) | ((uint)f2bf(s.y) << 16);
    float2* vp0 = (float2*)(vec + (size_t)n * 384) + lane;
    float2* vp1 = (float2*)(vec + (size_t)n * 384 + 128) + lane;
    float2* vp2 = (float2*)(vec + (size_t)n * 384 + 256) + lane;
    float2 v0 = *vp0, v1 = *vp1, v2 = *vp2;
    v0.x += aV00; v0.y += aV01;
    v1.x += aV10; v1.y += aV11;
    v2.x += aV20; v2.y += aV21;
    *vp0 = v0; *vp1 = v1; *vp2 = v2;
    uint* ob = (uint*)(vbout + (size_t)n * 384);
    ob[lane] = (uint)f2bf(v0.x) | ((uint)f2bf(v0.y) << 16);
    ob[lane + 64] = (uint)f2bf(v1.x) | ((uint)f2bf(v1.y) << 16);
    ob[lane + 128] = (uint)f2bf(v2.x) | ((uint)f2bf(v2.y) << 16);
  }
}

// ---------------- fused 2-layer MLP: out = silu(A@W1^T+b1)@W2^T+b2 ----------------
// A [M,K1] bf16, W1T [128,K1] bf16, W2T [384,128] bf16, out [M,384]
template <bool OUTBF>
__global__ __launch_bounds__(256) void mlp_kernel(const ushort* __restrict__ A,
                                                  const ushort* __restrict__ W1T,
                                                  const float* __restrict__ b1,
                                                  const ushort* __restrict__ W2T,
                                                  const float* __restrict__ b2,
                                                  void* __restrict__ out, int M, int K1) {
  __shared__ ushort As[32 * 128];
  __shared__ ushort Bs[128 * 128];
  __shared__ ushort Hs[32 * 128];
  int tid = threadIdx.x;
  int lane = tid & 63, w = tid >> 6;
  int mh = w >> 1, wc = w & 1;
  int m0 = blockIdx.x * 32;
  int cl = lane & 15, rq = lane >> 4;
  f32x4 acc[4] = {};
  for (int k0 = 0; k0 < K1; k0 += 128) {
    __syncthreads();
#pragma unroll
    for (int r = 0; r < 2; ++r) {  // A tile 32x128
      int c = tid + r * 256;
      int row = c >> 4, ch = c & 15;
      uint4 av = make_uint4(0, 0, 0, 0);
      if (m0 + row < M) av = *(const uint4*)(A + (size_t)(m0 + row) * K1 + k0 + ch * 8);
      *(uint4*)(&As[row * 128 + ((ch ^ (row & 7)) * 8)]) = av;
    }
#pragma unroll
    for (int r = 0; r < 8; ++r) {  // W1 tile 128x128
      int c = tid + r * 256;
      int row = c >> 4, ch = c & 15;
      uint4 bv = *(const uint4*)(W1T + (size_t)row * K1 + k0 + ch * 8);
      *(uint4*)(&Bs[row * 128 + ((ch ^ (row & 7)) * 8)]) = bv;
    }
    __syncthreads();
#pragma unroll
    for (int ks = 0; ks < 4; ++ks) {
      int ch = ks * 4 + rq;
      int ra = mh * 16 + cl;
      bf16x8 a = *(bf16x8*)&As[ra * 128 + ((ch ^ (ra & 7)) * 8)];
#pragma unroll
      for (int ns = 0; ns < 4; ++ns) {
        int rb = wc * 64 + ns * 16 + cl;
        bf16x8 b = *(bf16x8*)&Bs[rb * 128 + ((ch ^ (rb & 7)) * 8)];
        acc[ns] = __builtin_amdgcn_mfma_f32_16x16x32_bf16(a, b, acc[ns], 0, 0, 0);
      }
    }
  }
  // hidden: bias + silu -> Hs (bf16, swizzled)
#pragma unroll
  for (int ns = 0; ns < 4; ++ns) {
    int hcol = wc * 64 + ns * 16 + cl;
    float bv = b1[hcol];
    int chunk = hcol >> 3, el = hcol & 7;
#pragma unroll
    for (int j = 0; j < 4; ++j) {
      int hr = mh * 16 + rq * 4 + j;
      float v = silu_f(acc[ns][j] + bv);
      Hs[hr * 128 + ((chunk ^ (hr & 7)) * 8) + el] = f2bf(v);
    }
  }
  __syncthreads();
  // stage 2: 3 column-tiles of 128
  for (int nt = 0; nt < 3; ++nt) {
#pragma unroll
    for (int r = 0; r < 8; ++r) {
      int c = tid + r * 256;
      int row = c >> 4, ch = c & 15;
      uint4 bv = *(const uint4*)(W2T + (size_t)(nt * 128 + row) * 128 + ch * 8);
      *(uint4*)(&Bs[row * 128 + ((ch ^ (row & 7)) * 8)]) = bv;
    }
    __syncthreads();
    f32x4 acc2[4] = {};
#pragma unroll
    for (int ks = 0; ks < 4; ++ks) {
      int ch = ks * 4 + rq;
      int ra = mh * 16 + cl;
      bf16x8 a = *(bf16x8*)&Hs[ra * 128 + ((ch ^ (ra & 7)) * 8)];
#pragma unroll
      for (int ns = 0; ns < 4; ++ns) {
        int rb = wc * 64 + ns * 16 + cl;
        bf16x8 b = *(bf16x8*)&Bs[rb * 128 + ((ch ^ (rb & 7)) * 8)];
        acc2[ns] = __builtin_amdgcn_mfma_f32_16x16x32_bf16(a, b, acc2[ns], 0, 0, 0);
      }
    }
#pragma unroll
    for (int ns = 0; ns < 4; ++ns) {
      int col = nt * 128 + wc * 64 + ns * 16 + cl;
      float bv = b2[col];
#pragma unroll
      for (int j = 0; j < 4; ++j) {
        int m = m0 + mh * 16 + rq * 4 + j;
        if (m >= M) continue;
        float v = acc2[ns][j] + bv;
        if (OUTBF)
          ((ushort*)out)[(size_t)m * 384 + col] = f2bf(v);
        else
          ((float*)out)[(size_t)m * 384 + col] = v;
      }
    }
    __syncthreads();
  }
}

// ---------------- bf16 MFMA GEMM: C = act(A[M,K] @ WT[N,K]^T + b) ----------------
template <bool SILU, bool HASB, bool OUTBF>
__global__ __launch_bounds__(256) void gemm_kernel(const ushort* __restrict__ A,
                                                   const ushort* __restrict__ WT,
                                                   const float* __restrict__ bias,
                                                   void* __restrict__ Cout, int M, int K, int Nn) {
  __shared__ ushort As[64 * 128];
  __shared__ ushort Bs[64 * 128];
  int tid = threadIdx.x;
  int m0 = blockIdx.x * 64, n0 = blockIdx.y * 64;
  int lane = tid & 63, w = tid >> 6, wr = w >> 1, wc = w & 1;
  f32x4 acc[2][2] = {};
  for (int k0 = 0; k0 < K; k0 += 128) {
    __syncthreads();
#pragma unroll
    for (int r = 0; r < 4; ++r) {
      int c = tid + r * 256;
      int row = c >> 4, col16 = c & 15;
      uint4 av = make_uint4(0, 0, 0, 0);
      if (m0 + row < M) av = *(const uint4*)(A + (size_t)(m0 + row) * K + k0 + col16 * 8);
      *(uint4*)(&As[row * 128 + ((col16 ^ (row & 7)) * 8)]) = av;
      uint4 bv = *(const uint4*)(WT + (size_t)(n0 + row) * K + k0 + col16 * 8);
      *(uint4*)(&Bs[row * 128 + ((col16 ^ (row & 7)) * 8)]) = bv;
    }
    __syncthreads();
#pragma unroll
    for (int ks = 0; ks < 4; ++ks) {
      int ch = ks * 4 + (lane >> 4);
      int ra0 = wr * 32 + (lane & 15), ra1 = ra0 + 16;
      int rb0 = wc * 32 + (lane & 15), rb1 = rb0 + 16;
      bf16x8 a0 = *(bf16x8*)&As[ra0 * 128 + ((ch ^ (ra0 & 7)) * 8)];
      bf16x8 a1 = *(bf16x8*)&As[ra1 * 128 + ((ch ^ (ra1 & 7)) * 8)];
      bf16x8 b0 = *(bf16x8*)&Bs[rb0 * 128 + ((ch ^ (rb0 & 7)) * 8)];
      bf16x8 b1 = *(bf16x8*)&Bs[rb1 * 128 + ((ch ^ (rb1 & 7)) * 8)];
      acc[0][0] = __builtin_amdgcn_mfma_f32_16x16x32_bf16(a0, b0, acc[0][0], 0, 0, 0);
      acc[0][1] = __builtin_amdgcn_mfma_f32_16x16x32_bf16(a0, b1, acc[0][1], 0, 0, 0);
      acc[1][0] = __builtin_amdgcn_mfma_f32_16x16x32_bf16(a1, b0, acc[1][0], 0, 0, 0);
      acc[1][1] = __builtin_amdgcn_mfma_f32_16x16x32_bf16(a1, b1, acc[1][1], 0, 0, 0);
    }
  }
  int cl = lane & 15, rq = lane >> 4;
#pragma unroll
  for (int ms = 0; ms < 2; ++ms)
#pragma unroll
    for (int ns = 0; ns < 2; ++ns) {
      int n = n0 + wc * 32 + ns * 16 + cl;
      float bv = HASB ? bias[n] : 0.0f;
#pragma unroll
      for (int j = 0; j < 4; ++j) {
        int m = m0 + wr * 32 + ms * 16 + rq * 4 + j;
        if (m >= M) continue;
        float v = acc[ms][ns][j] + bv;
        if (SILU) v = silu_f(v);
        if (OUTBF)
          ((ushort*)Cout)[(size_t)m * Nn + n] = f2bf(v);
        else
          ((float*)Cout)[(size_t)m * Nn + n] = v;
      }
    }
}

// ---------------- v_norm + concat(scalar_bf, v_norm) -> bf16 ----------------
__global__ void vnorm_kernel(const float* __restrict__ uvvv, const ushort* __restrict__ sbf,
                             ushort* __restrict__ cat, int N) {
  int idx = blockIdx.x * 256 + threadIdx.x;
  if (idx >= N * 128) return;
  int n = idx >> 7, j = idx & 127;
  const float* b = uvvv + (size_t)n * 768;
  float v0 = b[128 + j], v1 = b[384 + j], v2 = b[640 + j];
  float vn = sqrtf(v0 * v0 + v1 * v1 + v2 * v2 + 1e-8f);
  cat[(size_t)n * 256 + j] = sbf[idx];
  cat[(size_t)n * 256 + 128 + j] = f2bf(vn);
}

// ---------------- update combine ----------------
__global__ void combine_kernel(const float* __restrict__ uvvv, const float* __restrict__ a,
                               float* __restrict__ scalar, ushort* __restrict__ sbf,
                               float* __restrict__ vec, ushort* __restrict__ vbf, int N) {
  int idx = blockIdx.x * 256 + threadIdx.x;
  if (idx >= N * 128) return;
  int n = idx >> 7, j = idx & 127;
  const float* b = uvvv + (size_t)n * 768;
  float u0 = b[j], w0 = b[128 + j];
  float u1 = b[256 + j], w1 = b[384 + j];
  float u2 = b[512 + j], w2 = b[640 + j];
  float dot = u0 * w0 + u1 * w1 + u2 * w2;
  const float* ab = a + (size_t)n * 384;
  float a1 = ab[j], a2 = ab[128 + j], a3 = ab[256 + j];
  float s = scalar[idx] + a1 + a2 * dot;
  scalar[idx] = s;
  sbf[idx] = f2bf(s);
  size_t vb = (size_t)n * 384 + j;
  float nv0 = vec[vb] + a3 * u0;
  float nv1 = vec[vb + 128] + a3 * u1;
  float nv2 = vec[vb + 256] + a3 * u2;
  vec[vb] = nv0;
  vec[vb + 128] = nv1;
  vec[vb + 256] = nv2;
  vbf[vb] = f2bf(nv0);
  vbf[vb + 128] = f2bf(nv1);
  vbf[vb + 256] = f2bf(nv2);
}

// ---------------- readout ----------------
__global__ __launch_bounds__(256) void readout_kernel(const float* __restrict__ t3,
                                                      const float* __restrict__ r_w2,
                                                      const float* __restrict__ r_b2,
                                                      const int* __restrict__ bidx,
                                                      float* __restrict__ out, int N, int G) {
  __shared__ float sm[64];
  int tid = threadIdx.x;
  if (tid < 64) sm[tid] = 0.f;
  __syncthreads();
  int lane = tid & 63, wid = tid >> 6;
  float wv = r_w2[lane];
  float rb2 = r_b2[0];
  bool ldsG = (G <= 64);
  for (int n = blockIdx.x * 4 + wid; n < N; n += gridDim.x * 4) {
    float v = t3[(size_t)n * 64 + lane] * wv;
#pragma unroll
    for (int o = 32; o > 0; o >>= 1) v += __shfl_down(v, o);
    if (lane == 0) {
      int g = bidx[n];
      if (ldsG)
        atomicAdd(&sm[g], v + rb2);
      else
        atomicAdd(&out[g], v + rb2);
    }
  }
  __syncthreads();
  if (ldsG && tid < G) atomicAdd(&out[tid], sm[tid]);
}

extern "C" void kernel_launch(void* const* d_in, const int* in_sizes, int n_in, void* d_out,
                              int out_size, void* d_ws, size_t ws_size, hipStream_t stream) {
  const int N = in_sizes[0];
  const int E = in_sizes[2] / 2;
  const int G = out_size;

  const int* z = (const int*)d_in[0];
  const float* pos = (const float*)d_in[1];
  const int* ei = (const int*)d_in[2];
  const float* shifts = (const float*)d_in[3];
  const int* bidx = (const int*)d_in[4];
  const float* emb = (const float*)d_in[5];
  const float* m_w1 = (const float*)d_in[6];
  const float* m_b1 = (const float*)d_in[7];
  const float* m_w2 = (const float*)d_in[8];
  const float* m_b2 = (const float*)d_in[9];
  const float* f_w = (const float*)d_in[10];
  const float* f_b = (const float*)d_in[11];
  const float* u_w = (const float*)d_in[12];
  const float* v_w = (const float*)d_in[13];
  const float* up_w1 = (const float*)d_in[14];
  const float* up_b1 = (const float*)d_in[15];
  const float* up_w2 = (const float*)d_in[16];
  const float* up_b2 = (const float*)d_in[17];
  const float* r_w1 = (const float*)d_in[18];
  const float* r_b1 = (const float*)d_in[19];
  const float* r_w2 = (const float*)d_in[20];
  const float* r_b2 = (const float*)d_in[21];
  float* out = (float*)d_out;

  float* w = (float*)d_ws;
  size_t off = 0;
  auto alloc = [&](size_t nfl) { float* p = w + off; off += (nfl + 3) & ~(size_t)3; return p; };
  ushort* tab = (ushort*)alloc((size_t)3 * TL * 192);
  float* scalar = alloc((size_t)N * 128);
  ushort* sbf = (ushort*)alloc((size_t)N * 64);
  float* vec = alloc((size_t)N * 384);
  ushort* mirA = (ushort*)alloc((size_t)N * 192);
  ushort* mirB = (ushort*)alloc((size_t)N * 192);
  ushort* hn_bf = (ushort*)alloc((size_t)N * 192);
  ushort* cat_bf = (ushort*)alloc((size_t)N * 128);
  float* uvvv = alloc((size_t)N * 768);
  float* abuf = alloc((size_t)N * 384);
  float* t3 = alloc((size_t)N * 64);
  float* pkf = alloc((size_t)E * 8);
  ushort* wt = (ushort*)alloc((size_t)274432);
  int* counts = (int*)alloc((size_t)N);
  int* offs = (int*)alloc((size_t)N + 4);
  int* cursor = (int*)alloc((size_t)N);
  if (off * sizeof(float) > ws_size) return;

  hipMemsetAsync(counts, 0, (size_t)N * sizeof(int), stream);
  hipMemsetAsync(vec, 0, (size_t)N * 384 * sizeof(float), stream);
  hipMemsetAsync(mirA, 0, (size_t)N * 384 * sizeof(ushort), stream);
  hipMemsetAsync(out, 0, (size_t)G * sizeof(float), stream);

  emb_kernel<<<(N * 128 + 255) / 256, 256, 0, stream>>>(z, emb, scalar, sbf, N);
  wconv_kernel<<<(548864 + 255) / 256, 256, 0, stream>>>(m_w1, m_w2, u_w, v_w, up_w1, up_w2,
                                                         r_w1, wt);
  table_kernel<<<(3 * TL * 384 + 255) / 256, 256, 0, stream>>>(f_w, f_b, tab);
  count_kernel<<<(E + 255) / 256, 256, 0, stream>>>(pos, ei, shifts, counts, E);
  scan_kernel<<<1, 1024, 0, stream>>>(counts, offs, cursor, N);
  fill_kernel<<<(E + 255) / 256, 256, 0, stream>>>(pos, ei, shifts, cursor, (float4*)pkf, E);

  dim3 gm((N + 31) / 32);
  dim3 g3((3 * N + 63) / 64, 4);
  dim3 gr((N + 63) / 64, 1);
  int ge = (N * 128 + 255) / 256;

  for (int l = 0; l < 3; l++) {
    ushort* mir_in = (l & 1) ? mirB : mirA;
    ushort* mir_out = (l & 1) ? mirA : mirB;
    const ushort* wl = wt + (size_t)l * 180224;
    mlp_kernel<true><<<gm, 256, 0, stream>>>(sbf, wl, m_b1 + l * 128, wl + 16384, m_b2 + l * 384,
                                             hn_bf, N, 128);
    message_kernel<<<(N + 1) / 2, 256, 0, stream>>>(offs, (const float4*)pkf, (const uint*)hn_bf,
                                                    (const uint*)mir_in,
                                                    (const uint*)(tab + (size_t)l * TL * 384),
                                                    scalar, sbf, vec, mir_out, N);
    gemm_kernel<false, false, false><<<g3, 256, 0, stream>>>(mir_out, wl + 65536, nullptr, uvvv,
                                                             3 * N, 128, 256);
    vnorm_kernel<<<ge, 256, 0, stream>>>(uvvv, sbf, cat_bf, N);
    mlp_kernel<false><<<gm, 256, 0, stream>>>(cat_bf, wl + 98304, up_b1 + l * 128, wl + 131072,
                                              up_b2 + l * 384, abuf, N, 256);
    combine_kernel<<<ge, 256, 0, stream>>>(uvvv, abuf, scalar, sbf, vec, mir_out, N);
  }

  gemm_kernel<true, true, false><<<gr, 256, 0, stream>>>(sbf, wt + 540672, r_b1, t3, N, 128, 64);
  readout_kernel<<<64, 256, 0, stream>>>(t3, r_w2, r_b2, bidx, out, N, G);
}

// Round 5
// 433.299 us; speedup vs baseline: 2.5087x; 1.1442x over previous
//
#include <hip/hip_runtime.h>
#include <math.h>

#define CUTR 5.0f
#define TL 2048
#define NBASIS 32

typedef __attribute__((ext_vector_type(8))) short bf16x8;
typedef __attribute__((ext_vector_type(4))) float f32x4;

__device__ __forceinline__ float silu_f(float x) { return x / (1.0f + expf(-x)); }
__device__ __forceinline__ ushort f2bf(float x) {
  uint b = __float_as_uint(x);
  uint r = (b + 0x7FFFu + ((b >> 16) & 1u)) >> 16;
  return (ushort)r;
}
__device__ __forceinline__ float bf2f(ushort u) { return __uint_as_float((uint)u << 16); }
#define BFLO(u) __uint_as_float((u) << 16)
#define BFHI(u) __uint_as_float((u) & 0xFFFF0000u)

// ---------------- scalar init from embedding ----------------
__global__ void emb_kernel(const int* __restrict__ z, const float* __restrict__ emb,
                           float* __restrict__ scalar, ushort* __restrict__ sbf, int N) {
  int idx = blockIdx.x * 256 + threadIdx.x;
  if (idx >= N * 128) return;
  int n = idx >> 7, j = idx & 127;
  float v = emb[z[n] * 128 + j];
  scalar[idx] = v;
  sbf[idx] = f2bf(v);
}

// ---------------- weight convert + transpose to bf16 [N][K] ----------------
__global__ void wconv_kernel(const float* __restrict__ m_w1, const float* __restrict__ m_w2,
                             const float* __restrict__ u_w, const float* __restrict__ v_w,
                             const float* __restrict__ up_w1, const float* __restrict__ up_w2,
                             const float* __restrict__ r_w1, ushort* __restrict__ wt) {
  int idx = blockIdx.x * 256 + threadIdx.x;
  if (idx >= 548864) return;
  float v;
  if (idx >= 540672) {
    int t = idx - 540672;
    int n = t >> 7, k = t & 127;
    v = r_w1[k * 64 + n];
  } else {
    int l = idx / 180224, local = idx % 180224;
    if (local < 16384) {
      int n = local >> 7, k = local & 127;
      v = m_w1[l * 16384 + k * 128 + n];
    } else if (local < 65536) {
      int t = local - 16384;
      int n = t >> 7, k = t & 127;
      v = m_w2[l * 49152 + k * 384 + n];
    } else if (local < 98304) {
      int t = local - 65536;
      int n = t >> 7, k = t & 127;
      v = (n < 128) ? u_w[l * 16384 + k * 128 + n] : v_w[l * 16384 + k * 128 + (n - 128)];
    } else if (local < 131072) {
      int t = local - 98304;
      int n = t >> 8, k = t & 255;
      v = up_w1[l * 32768 + k * 128 + n];
    } else {
      int t = local - 131072;
      int n = t >> 7, k = t & 127;
      v = up_w2[l * 49152 + k * 384 + n];
    }
  }
  wt[idx] = f2bf(v);
}

// ---------------- radial filter table (bf16), shared-rbf version ----------------
// grid = 3*(TL/8) blocks x 384 threads; block handles 8 consecutive t for layer l
__global__ __launch_bounds__(384) void table_kernel(const float* __restrict__ f_w,
                                                    const float* __restrict__ f_b,
                                                    ushort* __restrict__ tab) {
  __shared__ float fws[NBASIS * 384];
  __shared__ float rbf[8][NBASIS];
  __shared__ float gv[8];
  int l = blockIdx.x >> 8, tb = blockIdx.x & 255;
  int tid = threadIdx.x;
  for (int i = tid; i < NBASIS * 384; i += 384) fws[i] = f_w[l * NBASIS * 384 + i];
  if (tid < 256) {
    int tt = tid >> 5, k = tid & 31;
    float len = (float)(tb * 8 + tt) * (CUTR / (float)(TL - 1));
    const float gamma = (31.0f / 5.0f) * (31.0f / 5.0f);
    float c = 5.0f * (float)k / 31.0f;
    float d = len - c;
    rbf[tt][k] = expf(-gamma * d * d);
    if (k == 0) {
      float s = len * (1.0f / CUTR);
      gv[tt] = (s < 1.0f) ? expf(1.0f - 1.0f / (1.0f - s * s)) : 0.0f;
    }
  }
  __syncthreads();
  int j = tid % 384;
  float fb = f_b[l * 384 + j];
  for (int tt = 0; tt < 8; ++tt) {
    float acc = 0.0f;
#pragma unroll
    for (int k = 0; k < NBASIS; ++k) acc += rbf[tt][k] * fws[k * 384 + j];
    float g = gv[tt];
    tab[(size_t)l * TL * 384 + (size_t)(tb * 8 + tt) * 384 + j] = f2bf(g * (g * acc + fb));
  }
}

// ---------------- CSR build over ACTIVE edges (len < CUT) ----------------
__global__ void count_kernel(const float* __restrict__ pos, const int* __restrict__ ei,
                             const float* __restrict__ shifts, int* __restrict__ counts, int E) {
  int e = blockIdx.x * 256 + threadIdx.x;
  if (e >= E) return;
  int r = ei[e], c = ei[E + e];
  float dx = pos[c * 3 + 0] - pos[r * 3 + 0] + shifts[e * 3 + 0];
  float dy = pos[c * 3 + 1] - pos[r * 3 + 1] + shifts[e * 3 + 1];
  float dz = pos[c * 3 + 2] - pos[r * 3 + 2] + shifts[e * 3 + 2];
  float len = sqrtf(dx * dx + dy * dy + dz * dz + 1e-12f);
  if (len < CUTR) atomicAdd(&counts[r], 1);
}

__global__ __launch_bounds__(1024) void scan_kernel(const int* __restrict__ counts,
                                                    int* __restrict__ offs,
                                                    int* __restrict__ cursor, int N) {
  __shared__ int sm[1024];
  int tid = threadIdx.x;
  int CH = (N + 1023) / 1024;
  int base = tid * CH;
  int sum = 0;
  for (int i = 0; i < CH; i++) sum += (base + i < N) ? counts[base + i] : 0;
  sm[tid] = sum;
  __syncthreads();
  for (int o = 1; o < 1024; o <<= 1) {
    int v = (tid >= o) ? sm[tid - o] : 0;
    __syncthreads();
    sm[tid] += v;
    __syncthreads();
  }
  int run = sm[tid] - sum;
  for (int i = 0; i < CH; i++) {
    if (base + i < N) {
      offs[base + i] = run;
      cursor[base + i] = run;
      run += counts[base + i];
    }
  }
  if (tid == 1023) offs[N] = sm[1023];
}

// packed edge record: x = (col | ib<<14) as int bits; yzw = unit direction
__global__ void fill_kernel(const float* __restrict__ pos, const int* __restrict__ ei,
                            const float* __restrict__ shifts, int* __restrict__ cursor,
                            float4* __restrict__ pk, int E) {
  int e = blockIdx.x * 256 + threadIdx.x;
  if (e >= E) return;
  int r = ei[e], c = ei[E + e];
  float dx = pos[c * 3 + 0] - pos[r * 3 + 0] + shifts[e * 3 + 0];
  float dy = pos[c * 3 + 1] - pos[r * 3 + 1] + shifts[e * 3 + 1];
  float dz = pos[c * 3 + 2] - pos[r * 3 + 2] + shifts[e * 3 + 2];
  float len = sqrtf(dx * dx + dy * dy + dz * dz + 1e-12f);
  if (len >= CUTR) return;
  float inv = 1.0f / len;
  float x = len * ((float)(TL - 1) / CUTR);
  int ib = (int)(x + 0.5f);
  if (ib > TL - 1) ib = TL - 1;
  int p = atomicAdd(&cursor[r], 1);
  pk[p] = make_float4(__int_as_float(c | (ib << 14)), dx * inv, dy * inv, dz * inv);
}

// ---------------- fused message: 2 waves/node, 2-edge unroll, pk prefetch ----------------
__global__ __launch_bounds__(256) void message_kernel(
    const int* __restrict__ offs, const float4* __restrict__ pk, const uint* __restrict__ hn,
    const uint* __restrict__ vbin, const uint* __restrict__ tab, float* __restrict__ scalar,
    ushort* __restrict__ sbf, float* __restrict__ vec, ushort* __restrict__ vbout, int N) {
  __shared__ float red[2][64][8];
  int tid = threadIdx.x;
  int lane = tid & 63;
  int w = tid >> 6, slot = w >> 1, half = w & 1;
  int n = blockIdx.x * 2 + slot;
  bool valid = (n < N);
  int p0 = 0, p1 = 0;
  if (valid) {
    p0 = offs[n];
    p1 = offs[n + 1];
  }
  float aS0 = 0.f, aS1 = 0.f;
  float aV00 = 0.f, aV01 = 0.f, aV10 = 0.f, aV11 = 0.f, aV20 = 0.f, aV21 = 0.f;
  int p = p0 + half;
  bool hasA = p < p1, hasB = p + 2 < p1;
  float4 cA, cB;
  if (hasA) cA = pk[p];
  if (hasB) cB = pk[p + 2];
  while (hasA) {
    int bitsA = __float_as_int(cA.x);
    int colA = bitsA & 16383, ibA = bitsA >> 14;
    const uint* hbA = hn + (size_t)colA * 192;
    const uint* vbA = vbin + (size_t)colA * 192;
    const uint* tbA = tab + (size_t)ibA * 192;
    uint hA1 = hbA[lane], hA2 = hbA[lane + 64], hA3 = hbA[lane + 128];
    uint vA0 = vbA[lane], vA1 = vbA[lane + 64], vA2 = vbA[lane + 128];
    uint tA1 = tbA[lane], tA2 = tbA[lane + 64], tA3 = tbA[lane + 128];
    uint hB1, hB2, hB3, vB0, vB1, vB2, tB1, tB2, tB3;
    float4 dB;
    if (hasB) {
      int bitsB = __float_as_int(cB.x);
      int colB = bitsB & 16383, ibB = bitsB >> 14;
      dB = cB;
      const uint* hbB = hn + (size_t)colB * 192;
      const uint* vbB = vbin + (size_t)colB * 192;
      const uint* tbB = tab + (size_t)ibB * 192;
      hB1 = hbB[lane]; hB2 = hbB[lane + 64]; hB3 = hbB[lane + 128];
      vB0 = vbB[lane]; vB1 = vbB[lane + 64]; vB2 = vbB[lane + 128];
      tB1 = tbB[lane]; tB2 = tbB[lane + 64]; tB3 = tbB[lane + 128];
    }
    // prefetch next pair's descriptors while gathers are in flight
    int pn = p + 4;
    bool nA = pn < p1, nB = pn + 2 < p1;
    float4 fA, fB;
    if (nA) fA = pk[pn];
    if (nB) fB = pk[pn + 2];
    // compute A
    {
      aS0 += BFLO(hA1) * BFLO(tA1);
      aS1 += BFHI(hA1) * BFHI(tA1);
      float w2l = BFLO(hA2) * BFLO(tA2), w2h = BFHI(hA2) * BFHI(tA2);
      float w3l = BFLO(hA3) * BFLO(tA3), w3h = BFHI(hA3) * BFHI(tA3);
      aV00 += BFLO(vA0) * w2l + w3l * cA.y;
      aV01 += BFHI(vA0) * w2h + w3h * cA.y;
      aV10 += BFLO(vA1) * w2l + w3l * cA.z;
      aV11 += BFHI(vA1) * w2h + w3h * cA.z;
      aV20 += BFLO(vA2) * w2l + w3l * cA.w;
      aV21 += BFHI(vA2) * w2h + w3h * cA.w;
    }
    if (hasB) {
      aS0 += BFLO(hB1) * BFLO(tB1);
      aS1 += BFHI(hB1) * BFHI(tB1);
      float w2l = BFLO(hB2) * BFLO(tB2), w2h = BFHI(hB2) * BFHI(tB2);
      float w3l = BFLO(hB3) * BFLO(tB3), w3h = BFHI(hB3) * BFHI(tB3);
      aV00 += BFLO(vB0) * w2l + w3l * dB.y;
      aV01 += BFHI(vB0) * w2h + w3h * dB.y;
      aV10 += BFLO(vB1) * w2l + w3l * dB.z;
      aV11 += BFHI(vB1) * w2h + w3h * dB.z;
      aV20 += BFLO(vB2) * w2l + w3l * dB.w;
      aV21 += BFHI(vB2) * w2h + w3h * dB.w;
    }
    cA = fA;
    cB = fB;
    hasA = nA;
    hasB = nB;
    p = pn;
  }
  if (half == 1) {
    float* r = &red[slot][lane][0];
    r[0] = aS0; r[1] = aS1;
    r[2] = aV00; r[3] = aV01;
    r[4] = aV10; r[5] = aV11;
    r[6] = aV20; r[7] = aV21;
  }
  __syncthreads();
  if (half == 0 && valid) {
    const float* r = &red[slot][lane][0];
    aS0 += r[0]; aS1 += r[1];
    aV00 += r[2]; aV01 += r[3];
    aV10 += r[4]; aV11 += r[5];
    aV20 += r[6]; aV21 += r[7];
    float2* sp = (float2*)(scalar + (size_t)n * 128) + lane;
    float2 s = *sp;
    s.x += aS0;
    s.y += aS1;
    *sp = s;
    ((uint*)(sbf + (size_t)n * 128))[lane] = (uint)f2bf(s.x) | ((uint)f2bf(s.y) << 16);
    float2* vp0 = (float2*)(vec + (size_t)n * 384) + lane;
    float2* vp1 = (float2*)(vec + (size_t)n * 384 + 128) + lane;
    float2* vp2 = (float2*)(vec + (size_t)n * 384 + 256) + lane;
    float2 v0 = *vp0, v1 = *vp1, v2 = *vp2;
    v0.x += aV00; v0.y += aV01;
    v1.x += aV10; v1.y += aV11;
    v2.x += aV20; v2.y += aV21;
    *vp0 = v0; *vp1 = v1; *vp2 = v2;
    uint* ob = (uint*)(vbout + (size_t)n * 384);
    ob[lane] = (uint)f2bf(v0.x) | ((uint)f2bf(v0.y) << 16);
    ob[lane + 64] = (uint)f2bf(v1.x) | ((uint)f2bf(v1.y) << 16);
    ob[lane + 128] = (uint)f2bf(v2.x) | ((uint)f2bf(v2.y) << 16);
  }
}

// ---------------- message MLP: hn = silu(sbf@W1^T+b1)@W2^T+b2 -> bf16 ----------------
__global__ __launch_bounds__(256) void mlp_kernel(const ushort* __restrict__ A,
                                                  const ushort* __restrict__ W1T,
                                                  const float* __restrict__ b1,
                                                  const ushort* __restrict__ W2T,
                                                  const float* __restrict__ b2,
                                                  ushort* __restrict__ out, int M) {
  __shared__ ushort As[32 * 128];
  __shared__ ushort Bs[128 * 128];
  __shared__ ushort Hs[32 * 128];
  int tid = threadIdx.x;
  int lane = tid & 63, w = tid >> 6;
  int mh = w >> 1, wc = w & 1;
  int m0 = blockIdx.x * 32;
  int cl = lane & 15, rq = lane >> 4;
  f32x4 acc[4] = {};
  {
    __syncthreads();
#pragma unroll
    for (int r = 0; r < 2; ++r) {
      int c = tid + r * 256;
      int row = c >> 4, ch = c & 15;
      uint4 av = make_uint4(0, 0, 0, 0);
      if (m0 + row < M) av = *(const uint4*)(A + (size_t)(m0 + row) * 128 + ch * 8);
      *(uint4*)(&As[row * 128 + ((ch ^ (row & 7)) * 8)]) = av;
    }
#pragma unroll
    for (int r = 0; r < 8; ++r) {
      int c = tid + r * 256;
      int row = c >> 4, ch = c & 15;
      uint4 bv = *(const uint4*)(W1T + (size_t)row * 128 + ch * 8);
      *(uint4*)(&Bs[row * 128 + ((ch ^ (row & 7)) * 8)]) = bv;
    }
    __syncthreads();
#pragma unroll
    for (int ks = 0; ks < 4; ++ks) {
      int ch = ks * 4 + rq;
      int ra = mh * 16 + cl;
      bf16x8 a = *(bf16x8*)&As[ra * 128 + ((ch ^ (ra & 7)) * 8)];
#pragma unroll
      for (int ns = 0; ns < 4; ++ns) {
        int rb = wc * 64 + ns * 16 + cl;
        bf16x8 b = *(bf16x8*)&Bs[rb * 128 + ((ch ^ (rb & 7)) * 8)];
        acc[ns] = __builtin_amdgcn_mfma_f32_16x16x32_bf16(a, b, acc[ns], 0, 0, 0);
      }
    }
  }
#pragma unroll
  for (int ns = 0; ns < 4; ++ns) {
    int hcol = wc * 64 + ns * 16 + cl;
    float bv = b1[hcol];
    int chunk = hcol >> 3, el = hcol & 7;
#pragma unroll
    for (int j = 0; j < 4; ++j) {
      int hr = mh * 16 + rq * 4 + j;
      float v = silu_f(acc[ns][j] + bv);
      Hs[hr * 128 + ((chunk ^ (hr & 7)) * 8) + el] = f2bf(v);
    }
  }
  __syncthreads();
  for (int nt = 0; nt < 3; ++nt) {
#pragma unroll
    for (int r = 0; r < 8; ++r) {
      int c = tid + r * 256;
      int row = c >> 4, ch = c & 15;
      uint4 bv = *(const uint4*)(W2T + (size_t)(nt * 128 + row) * 128 + ch * 8);
      *(uint4*)(&Bs[row * 128 + ((ch ^ (row & 7)) * 8)]) = bv;
    }
    __syncthreads();
    f32x4 acc2[4] = {};
#pragma unroll
    for (int ks = 0; ks < 4; ++ks) {
      int ch = ks * 4 + rq;
      int ra = mh * 16 + cl;
      bf16x8 a = *(bf16x8*)&Hs[ra * 128 + ((ch ^ (ra & 7)) * 8)];
#pragma unroll
      for (int ns = 0; ns < 4; ++ns) {
        int rb = wc * 64 + ns * 16 + cl;
        bf16x8 b = *(bf16x8*)&Bs[rb * 128 + ((ch ^ (rb & 7)) * 8)];
        acc2[ns] = __builtin_amdgcn_mfma_f32_16x16x32_bf16(a, b, acc2[ns], 0, 0, 0);
      }
    }
#pragma unroll
    for (int ns = 0; ns < 4; ++ns) {
      int col = nt * 128 + wc * 64 + ns * 16 + cl;
      float bv = b2[col];
#pragma unroll
      for (int j = 0; j < 4; ++j) {
        int m = m0 + mh * 16 + rq * 4 + j;
        if (m >= M) continue;
        out[(size_t)m * 384 + col] = f2bf(acc2[ns][j] + bv);
      }
    }
    __syncthreads();
  }
}

// ---------------- fused update MLP + combine ----------------
// A-half1 = sbf [N,128]; A-half2 = vnorm computed from uvvv (bf16, [N,3,{uv,vv}] node stride 768)
// epilogue: a1,a2,a3 held in regs -> scalar/vec/sbf/mir updates in-kernel
__global__ __launch_bounds__(256) void mlp2_kernel(const ushort* __restrict__ sbf_in,
                                                   const ushort* __restrict__ W1T,
                                                   const float* __restrict__ b1,
                                                   const ushort* __restrict__ W2T,
                                                   const float* __restrict__ b2,
                                                   const ushort* __restrict__ uvvv,
                                                   float* __restrict__ scalar,
                                                   ushort* __restrict__ sbf,
                                                   float* __restrict__ vec,
                                                   ushort* __restrict__ vbf, int M) {
  __shared__ ushort As[32 * 128];
  __shared__ ushort Bs[128 * 128];
  __shared__ ushort Hs[32 * 128];
  int tid = threadIdx.x;
  int lane = tid & 63, w = tid >> 6;
  int mh = w >> 1, wc = w & 1;
  int m0 = blockIdx.x * 32;
  int cl = lane & 15, rq = lane >> 4;
  f32x4 acc[4] = {};
  for (int k0 = 0; k0 < 256; k0 += 128) {
    __syncthreads();
#pragma unroll
    for (int r = 0; r < 2; ++r) {
      int c = tid + r * 256;
      int row = c >> 4, ch = c & 15;
      uint4 av = make_uint4(0, 0, 0, 0);
      if (m0 + row < M) {
        if (k0 == 0) {
          av = *(const uint4*)(sbf_in + (size_t)(m0 + row) * 128 + ch * 8);
        } else {
          const ushort* ub = uvvv + (size_t)(m0 + row) * 768 + 128 + ch * 8;
          bf16x8 x0 = *(const bf16x8*)(ub);
          bf16x8 x1 = *(const bf16x8*)(ub + 256);
          bf16x8 x2 = *(const bf16x8*)(ub + 512);
          ushort pkv[8];
#pragma unroll
          for (int e = 0; e < 8; ++e) {
            float a = bf2f((ushort)x0[e]), bb = bf2f((ushort)x1[e]), cc = bf2f((ushort)x2[e]);
            pkv[e] = f2bf(sqrtf(a * a + bb * bb + cc * cc + 1e-8f));
          }
          av = *(uint4*)pkv;
        }
      }
      *(uint4*)(&As[row * 128 + ((ch ^ (row & 7)) * 8)]) = av;
    }
#pragma unroll
    for (int r = 0; r < 8; ++r) {
      int c = tid + r * 256;
      int row = c >> 4, ch = c & 15;
      uint4 bv = *(const uint4*)(W1T + (size_t)row * 256 + k0 + ch * 8);
      *(uint4*)(&Bs[row * 128 + ((ch ^ (row & 7)) * 8)]) = bv;
    }
    __syncthreads();
#pragma unroll
    for (int ks = 0; ks < 4; ++ks) {
      int ch = ks * 4 + rq;
      int ra = mh * 16 + cl;
      bf16x8 a = *(bf16x8*)&As[ra * 128 + ((ch ^ (ra & 7)) * 8)];
#pragma unroll
      for (int ns = 0; ns < 4; ++ns) {
        int rb = wc * 64 + ns * 16 + cl;
        bf16x8 b = *(bf16x8*)&Bs[rb * 128 + ((ch ^ (rb & 7)) * 8)];
        acc[ns] = __builtin_amdgcn_mfma_f32_16x16x32_bf16(a, b, acc[ns], 0, 0, 0);
      }
    }
  }
#pragma unroll
  for (int ns = 0; ns < 4; ++ns) {
    int hcol = wc * 64 + ns * 16 + cl;
    float bv = b1[hcol];
    int chunk = hcol >> 3, el = hcol & 7;
#pragma unroll
    for (int j = 0; j < 4; ++j) {
      int hr = mh * 16 + rq * 4 + j;
      float v = silu_f(acc[ns][j] + bv);
      Hs[hr * 128 + ((chunk ^ (hr & 7)) * 8) + el] = f2bf(v);
    }
  }
  __syncthreads();
  f32x4 aReg[3][4];
  for (int nt = 0; nt < 3; ++nt) {
#pragma unroll
    for (int r = 0; r < 8; ++r) {
      int c = tid + r * 256;
      int row = c >> 4, ch = c & 15;
      uint4 bv = *(const uint4*)(W2T + (size_t)(nt * 128 + row) * 128 + ch * 8);
      *(uint4*)(&Bs[row * 128 + ((ch ^ (row & 7)) * 8)]) = bv;
    }
    __syncthreads();
    f32x4 acc2[4] = {};
#pragma unroll
    for (int ks = 0; ks < 4; ++ks) {
      int ch = ks * 4 + rq;
      int ra = mh * 16 + cl;
      bf16x8 a = *(bf16x8*)&Hs[ra * 128 + ((ch ^ (ra & 7)) * 8)];
#pragma unroll
      for (int ns = 0; ns < 4; ++ns) {
        int rb = wc * 64 + ns * 16 + cl;
        bf16x8 b = *(bf16x8*)&Bs[rb * 128 + ((ch ^ (rb & 7)) * 8)];
        acc2[ns] = __builtin_amdgcn_mfma_f32_16x16x32_bf16(a, b, acc2[ns], 0, 0, 0);
      }
    }
#pragma unroll
    for (int ns = 0; ns < 4; ++ns) aReg[nt][ns] = acc2[ns];
    __syncthreads();
  }
  // fused combine epilogue
#pragma unroll
  for (int ns = 0; ns < 4; ++ns) {
    int chOff = wc * 64 + ns * 16 + cl;
    float b2a = b2[chOff], b2b = b2[128 + chOff], b2c = b2[256 + chOff];
#pragma unroll
    for (int j = 0; j < 4; ++j) {
      int nn = m0 + mh * 16 + rq * 4 + j;
      if (nn >= M) continue;
      float a1 = aReg[0][ns][j] + b2a;
      float a2 = aReg[1][ns][j] + b2b;
      float a3 = aReg[2][ns][j] + b2c;
      const ushort* ub = uvvv + (size_t)nn * 768;
      float uv0 = bf2f(ub[chOff]), vv0 = bf2f(ub[128 + chOff]);
      float uv1 = bf2f(ub[256 + chOff]), vv1 = bf2f(ub[384 + chOff]);
      float uv2 = bf2f(ub[512 + chOff]), vv2 = bf2f(ub[640 + chOff]);
      float dot = uv0 * vv0 + uv1 * vv1 + uv2 * vv2;
      size_t si = (size_t)nn * 128 + chOff;
      float s = scalar[si] + a1 + a2 * dot;
      scalar[si] = s;
      sbf[si] = f2bf(s);
      size_t vb = (size_t)nn * 384 + chOff;
      float nv0 = vec[vb] + a3 * uv0;
      float nv1 = vec[vb + 128] + a3 * uv1;
      float nv2 = vec[vb + 256] + a3 * uv2;
      vec[vb] = nv0;
      vec[vb + 128] = nv1;
      vec[vb + 256] = nv2;
      vbf[vb] = f2bf(nv0);
      vbf[vb + 128] = f2bf(nv1);
      vbf[vb + 256] = f2bf(nv2);
    }
  }
}

// ---------------- bf16 MFMA GEMM: C = act(A[M,K] @ WT[N,K]^T + b) ----------------
template <bool SILU, bool HASB, bool OUTBF>
__global__ __launch_bounds__(256) void gemm_kernel(const ushort* __restrict__ A,
                                                   const ushort* __restrict__ WT,
                                                   const float* __restrict__ bias,
                                                   void* __restrict__ Cout, int M, int K, int Nn) {
  __shared__ ushort As[64 * 128];
  __shared__ ushort Bs[64 * 128];
  int tid = threadIdx.x;
  int m0 = blockIdx.x * 64, n0 = blockIdx.y * 64;
  int lane = tid & 63, w = tid >> 6, wr = w >> 1, wc = w & 1;
  f32x4 acc[2][2] = {};
  for (int k0 = 0; k0 < K; k0 += 128) {
    __syncthreads();
#pragma unroll
    for (int r = 0; r < 4; ++r) {
      int c = tid + r * 256;
      int row = c >> 4, col16 = c & 15;
      uint4 av = make_uint4(0, 0, 0, 0);
      if (m0 + row < M) av = *(const uint4*)(A + (size_t)(m0 + row) * K + k0 + col16 * 8);
      *(uint4*)(&As[row * 128 + ((col16 ^ (row & 7)) * 8)]) = av;
      uint4 bv = *(const uint4*)(WT + (size_t)(n0 + row) * K + k0 + col16 * 8);
      *(uint4*)(&Bs[row * 128 + ((col16 ^ (row & 7)) * 8)]) = bv;
    }
    __syncthreads();
#pragma unroll
    for (int ks = 0; ks < 4; ++ks) {
      int ch = ks * 4 + (lane >> 4);
      int ra0 = wr * 32 + (lane & 15), ra1 = ra0 + 16;
      int rb0 = wc * 32 + (lane & 15), rb1 = rb0 + 16;
      bf16x8 a0 = *(bf16x8*)&As[ra0 * 128 + ((ch ^ (ra0 & 7)) * 8)];
      bf16x8 a1 = *(bf16x8*)&As[ra1 * 128 + ((ch ^ (ra1 & 7)) * 8)];
      bf16x8 b0 = *(bf16x8*)&Bs[rb0 * 128 + ((ch ^ (rb0 & 7)) * 8)];
      bf16x8 b1 = *(bf16x8*)&Bs[rb1 * 128 + ((ch ^ (rb1 & 7)) * 8)];
      acc[0][0] = __builtin_amdgcn_mfma_f32_16x16x32_bf16(a0, b0, acc[0][0], 0, 0, 0);
      acc[0][1] = __builtin_amdgcn_mfma_f32_16x16x32_bf16(a0, b1, acc[0][1], 0, 0, 0);
      acc[1][0] = __builtin_amdgcn_mfma_f32_16x16x32_bf16(a1, b0, acc[1][0], 0, 0, 0);
      acc[1][1] = __builtin_amdgcn_mfma_f32_16x16x32_bf16(a1, b1, acc[1][1], 0, 0, 0);
    }
  }
  int cl = lane & 15, rq = lane >> 4;
#pragma unroll
  for (int ms = 0; ms < 2; ++ms)
#pragma unroll
    for (int ns = 0; ns < 2; ++ns) {
      int n = n0 + wc * 32 + ns * 16 + cl;
      float bv = HASB ? bias[n] : 0.0f;
#pragma unroll
      for (int j = 0; j < 4; ++j) {
        int m = m0 + wr * 32 + ms * 16 + rq * 4 + j;
        if (m >= M) continue;
        float v = acc[ms][ns][j] + bv;
        if (SILU) v = silu_f(v);
        if (OUTBF)
          ((ushort*)Cout)[(size_t)m * Nn + n] = f2bf(v);
        else
          ((float*)Cout)[(size_t)m * Nn + n] = v;
      }
    }
}

// ---------------- readout ----------------
__global__ __launch_bounds__(256) void readout_kernel(const float* __restrict__ t3,
                                                      const float* __restrict__ r_w2,
                                                      const float* __restrict__ r_b2,
                                                      const int* __restrict__ bidx,
                                                      float* __restrict__ out, int N, int G) {
  __shared__ float sm[64];
  int tid = threadIdx.x;
  if (tid < 64) sm[tid] = 0.f;
  __syncthreads();
  int lane = tid & 63, wid = tid >> 6;
  float wv = r_w2[lane];
  float rb2 = r_b2[0];
  bool ldsG = (G <= 64);
  for (int n = blockIdx.x * 4 + wid; n < N; n += gridDim.x * 4) {
    float v = t3[(size_t)n * 64 + lane] * wv;
#pragma unroll
    for (int o = 32; o > 0; o >>= 1) v += __shfl_down(v, o);
    if (lane == 0) {
      int g = bidx[n];
      if (ldsG)
        atomicAdd(&sm[g], v + rb2);
      else
        atomicAdd(&out[g], v + rb2);
    }
  }
  __syncthreads();
  if (ldsG && tid < G) atomicAdd(&out[tid], sm[tid]);
}

extern "C" void kernel_launch(void* const* d_in, const int* in_sizes, int n_in, void* d_out,
                              int out_size, void* d_ws, size_t ws_size, hipStream_t stream) {
  const int N = in_sizes[0];
  const int E = in_sizes[2] / 2;
  const int G = out_size;

  const int* z = (const int*)d_in[0];
  const float* pos = (const float*)d_in[1];
  const int* ei = (const int*)d_in[2];
  const float* shifts = (const float*)d_in[3];
  const int* bidx = (const int*)d_in[4];
  const float* emb = (const float*)d_in[5];
  const float* m_w1 = (const float*)d_in[6];
  const float* m_b1 = (const float*)d_in[7];
  const float* m_w2 = (const float*)d_in[8];
  const float* m_b2 = (const float*)d_in[9];
  const float* f_w = (const float*)d_in[10];
  const float* f_b = (const float*)d_in[11];
  const float* u_w = (const float*)d_in[12];
  const float* v_w = (const float*)d_in[13];
  const float* up_w1 = (const float*)d_in[14];
  const float* up_b1 = (const float*)d_in[15];
  const float* up_w2 = (const float*)d_in[16];
  const float* up_b2 = (const float*)d_in[17];
  const float* r_w1 = (const float*)d_in[18];
  const float* r_b1 = (const float*)d_in[19];
  const float* r_w2 = (const float*)d_in[20];
  const float* r_b2 = (const float*)d_in[21];
  float* out = (float*)d_out;

  float* w = (float*)d_ws;
  size_t off = 0;
  auto alloc = [&](size_t nfl) { float* p = w + off; off += (nfl + 3) & ~(size_t)3; return p; };
  ushort* tab = (ushort*)alloc((size_t)3 * TL * 192);
  float* scalar = alloc((size_t)N * 128);
  ushort* sbf = (ushort*)alloc((size_t)N * 64);
  float* vec = alloc((size_t)N * 384);
  ushort* mirA = (ushort*)alloc((size_t)N * 192);
  ushort* mirB = (ushort*)alloc((size_t)N * 192);
  ushort* hn_bf = (ushort*)alloc((size_t)N * 192);
  ushort* uvvv = (ushort*)alloc((size_t)N * 384);  // [3N,256] bf16
  float* t3 = alloc((size_t)N * 64);
  float* pkf = alloc((size_t)E * 4);
  ushort* wt = (ushort*)alloc((size_t)274432);
  int* counts = (int*)alloc((size_t)N);
  int* offs = (int*)alloc((size_t)N + 4);
  int* cursor = (int*)alloc((size_t)N);
  if (off * sizeof(float) > ws_size) return;

  hipMemsetAsync(counts, 0, (size_t)N * sizeof(int), stream);
  hipMemsetAsync(vec, 0, (size_t)N * 384 * sizeof(float), stream);
  hipMemsetAsync(mirA, 0, (size_t)N * 384 * sizeof(ushort), stream);
  hipMemsetAsync(out, 0, (size_t)G * sizeof(float), stream);

  emb_kernel<<<(N * 128 + 255) / 256, 256, 0, stream>>>(z, emb, scalar, sbf, N);
  wconv_kernel<<<(548864 + 255) / 256, 256, 0, stream>>>(m_w1, m_w2, u_w, v_w, up_w1, up_w2,
                                                         r_w1, wt);
  table_kernel<<<3 * (TL / 8), 384, 0, stream>>>(f_w, f_b, tab);
  count_kernel<<<(E + 255) / 256, 256, 0, stream>>>(pos, ei, shifts, counts, E);
  scan_kernel<<<1, 1024, 0, stream>>>(counts, offs, cursor, N);
  fill_kernel<<<(E + 255) / 256, 256, 0, stream>>>(pos, ei, shifts, cursor, (float4*)pkf, E);

  dim3 gm((N + 31) / 32);
  dim3 g3((3 * N + 63) / 64, 4);
  dim3 gr((N + 63) / 64, 1);

  for (int l = 0; l < 3; l++) {
    ushort* mir_in = (l & 1) ? mirB : mirA;
    ushort* mir_out = (l & 1) ? mirA : mirB;
    const ushort* wl = wt + (size_t)l * 180224;
    mlp_kernel<<<gm, 256, 0, stream>>>(sbf, wl, m_b1 + l * 128, wl + 16384, m_b2 + l * 384,
                                       hn_bf, N);
    message_kernel<<<(N + 1) / 2, 256, 0, stream>>>(offs, (const float4*)pkf, (const uint*)hn_bf,
                                                    (const uint*)mir_in,
                                                    (const uint*)(tab + (size_t)l * TL * 384),
                                                    scalar, sbf, vec, mir_out, N);
    gemm_kernel<false, false, true><<<g3, 256, 0, stream>>>(mir_out, wl + 65536, nullptr, uvvv,
                                                            3 * N, 128, 256);
    mlp2_kernel<<<gm, 256, 0, stream>>>(sbf, wl + 98304, up_b1 + l * 128, wl + 131072,
                                        up_b2 + l * 384, uvvv, scalar, sbf, vec, mir_out, N);
  }

  gemm_kernel<true, true, false><<<gr, 256, 0, stream>>>(sbf, wt + 540672, r_b1, t3, N, 128, 64);
  readout_kernel<<<64, 256, 0, stream>>>(t3, r_w2, r_b2, bidx, out, N, G);
}

// Round 6
// 401.111 us; speedup vs baseline: 2.7100x; 1.0802x over previous
//
#include <hip/hip_runtime.h>
#include <math.h>

#define CUTR 5.0f
#define TL 2048
#define NBASIS 32

typedef __attribute__((ext_vector_type(8))) short bf16x8;
typedef __attribute__((ext_vector_type(4))) float f32x4;

__device__ __forceinline__ float silu_f(float x) { return x / (1.0f + expf(-x)); }
__device__ __forceinline__ ushort f2bf(float x) {
  uint b = __float_as_uint(x);
  uint r = (b + 0x7FFFu + ((b >> 16) & 1u)) >> 16;
  return (ushort)r;
}
__device__ __forceinline__ float bf2f(ushort u) { return __uint_as_float((uint)u << 16); }
#define BFLO(u) __uint_as_float((u) << 16)
#define BFHI(u) __uint_as_float((u) & 0xFFFF0000u)

// ---------------- fused setup: table | emb | wconv | count (branch on blockIdx) ------------
__global__ __launch_bounds__(384) void setup_kernel(
    const int* __restrict__ z, const float* __restrict__ emb, float* __restrict__ scalar,
    ushort* __restrict__ sbf, const float* __restrict__ m_w1, const float* __restrict__ m_w2,
    const float* __restrict__ u_w, const float* __restrict__ v_w,
    const float* __restrict__ up_w1, const float* __restrict__ up_w2,
    const float* __restrict__ r_w1, ushort* __restrict__ wt, const float* __restrict__ f_w,
    const float* __restrict__ f_b, ushort* __restrict__ tab, const float* __restrict__ pos,
    const int* __restrict__ ei, const float* __restrict__ shifts, int* __restrict__ counts,
    int N, int E) {
  __shared__ float fws[NBASIS * 384];
  __shared__ float rbf[8][NBASIS];
  __shared__ float gv[8];
  int tid = threadIdx.x;
  int bi = blockIdx.x;
  const int NB_TABLE = 3 * (TL / 8);
  const int NB_EMB = (0x7FFFFFFF);  // computed below via ranges
  // ranges
  int nbEmb = (N * 128 + 383) / 384;
  int nbW = (548864 + 383) / 384;
  if (bi < NB_TABLE) {
    // ---- radial table ----
    int l = bi >> 8, tb = bi & 255;
    for (int i = tid; i < NBASIS * 384; i += 384) fws[i] = f_w[l * NBASIS * 384 + i];
    if (tid < 256) {
      int tt = tid >> 5, k = tid & 31;
      float len = (float)(tb * 8 + tt) * (CUTR / (float)(TL - 1));
      const float gamma = (31.0f / 5.0f) * (31.0f / 5.0f);
      float c = 5.0f * (float)k / 31.0f;
      float d = len - c;
      rbf[tt][k] = expf(-gamma * d * d);
      if (k == 0) {
        float s = len * (1.0f / CUTR);
        gv[tt] = (s < 1.0f) ? expf(1.0f - 1.0f / (1.0f - s * s)) : 0.0f;
      }
    }
    __syncthreads();
    int j = tid % 384;
    float fb = f_b[l * 384 + j];
    for (int tt = 0; tt < 8; ++tt) {
      float acc = 0.0f;
#pragma unroll
      for (int k = 0; k < NBASIS; ++k) acc += rbf[tt][k] * fws[k * 384 + j];
      float g = gv[tt];
      tab[(size_t)l * TL * 384 + (size_t)(tb * 8 + tt) * 384 + j] = f2bf(g * (g * acc + fb));
    }
    return;
  }
  bi -= NB_TABLE;
  if (bi < nbEmb) {
    int idx = bi * 384 + tid;
    if (idx >= N * 128) return;
    int n = idx >> 7, j = idx & 127;
    float v = emb[z[n] * 128 + j];
    scalar[idx] = v;
    sbf[idx] = f2bf(v);
    return;
  }
  bi -= nbEmb;
  if (bi < nbW) {
    int idx = bi * 384 + tid;
    if (idx >= 548864) return;
    float v;
    if (idx >= 540672) {
      int t = idx - 540672;
      int n = t >> 7, k = t & 127;
      v = r_w1[k * 64 + n];
    } else {
      int l = idx / 180224, local = idx % 180224;
      if (local < 16384) {
        int n = local >> 7, k = local & 127;
        v = m_w1[l * 16384 + k * 128 + n];
      } else if (local < 65536) {
        int t = local - 16384;
        int n = t >> 7, k = t & 127;
        v = m_w2[l * 49152 + k * 384 + n];
      } else if (local < 98304) {
        int t = local - 65536;
        int n = t >> 7, k = t & 127;
        v = (n < 128) ? u_w[l * 16384 + k * 128 + n] : v_w[l * 16384 + k * 128 + (n - 128)];
      } else if (local < 131072) {
        int t = local - 98304;
        int n = t >> 8, k = t & 255;
        v = up_w1[l * 32768 + k * 128 + n];
      } else {
        int t = local - 131072;
        int n = t >> 7, k = t & 127;
        v = up_w2[l * 49152 + k * 384 + n];
      }
    }
    wt[idx] = f2bf(v);
    return;
  }
  bi -= nbW;
  {
    int e = bi * 384 + tid;
    if (e >= E) return;
    int r = ei[e], c = ei[E + e];
    float dx = pos[c * 3 + 0] - pos[r * 3 + 0] + shifts[e * 3 + 0];
    float dy = pos[c * 3 + 1] - pos[r * 3 + 1] + shifts[e * 3 + 1];
    float dz = pos[c * 3 + 2] - pos[r * 3 + 2] + shifts[e * 3 + 2];
    float len = sqrtf(dx * dx + dy * dy + dz * dz + 1e-12f);
    if (len < CUTR) atomicAdd(&counts[r], 1);
  }
}

__global__ __launch_bounds__(1024) void scan_kernel(const int* __restrict__ counts,
                                                    int* __restrict__ offs,
                                                    int* __restrict__ cursor, int N) {
  __shared__ int sm[1024];
  int tid = threadIdx.x;
  int CH = (N + 1023) / 1024;
  int base = tid * CH;
  int sum = 0;
  for (int i = 0; i < CH; i++) sum += (base + i < N) ? counts[base + i] : 0;
  sm[tid] = sum;
  __syncthreads();
  for (int o = 1; o < 1024; o <<= 1) {
    int v = (tid >= o) ? sm[tid - o] : 0;
    __syncthreads();
    sm[tid] += v;
    __syncthreads();
  }
  int run = sm[tid] - sum;
  for (int i = 0; i < CH; i++) {
    if (base + i < N) {
      offs[base + i] = run;
      cursor[base + i] = run;
      run += counts[base + i];
    }
  }
  if (tid == 1023) offs[N] = sm[1023];
}

// packed edge record: x = (col | ib<<14) as int bits; yzw = unit direction
__global__ void fill_kernel(const float* __restrict__ pos, const int* __restrict__ ei,
                            const float* __restrict__ shifts, int* __restrict__ cursor,
                            float4* __restrict__ pk, int E) {
  int e = blockIdx.x * 256 + threadIdx.x;
  if (e >= E) return;
  int r = ei[e], c = ei[E + e];
  float dx = pos[c * 3 + 0] - pos[r * 3 + 0] + shifts[e * 3 + 0];
  float dy = pos[c * 3 + 1] - pos[r * 3 + 1] + shifts[e * 3 + 1];
  float dz = pos[c * 3 + 2] - pos[r * 3 + 2] + shifts[e * 3 + 2];
  float len = sqrtf(dx * dx + dy * dy + dz * dz + 1e-12f);
  if (len >= CUTR) return;
  float inv = 1.0f / len;
  float x = len * ((float)(TL - 1) / CUTR);
  int ib = (int)(x + 0.5f);
  if (ib > TL - 1) ib = TL - 1;
  int p = atomicAdd(&cursor[r], 1);
  pk[p] = make_float4(__int_as_float(c | (ib << 14)), dx * inv, dy * inv, dz * inv);
}

// ---------------- fused message: 2 waves/node, 4-edge unroll, pk prefetch ----------------
__global__ __launch_bounds__(256) void message_kernel(
    const int* __restrict__ offs, const float4* __restrict__ pk, const uint* __restrict__ hn,
    const uint* __restrict__ vbin, const uint* __restrict__ tab, float* __restrict__ scalar,
    ushort* __restrict__ sbf, float* __restrict__ vec, ushort* __restrict__ vbout, int N) {
  __shared__ float red[2][64][8];
  int tid = threadIdx.x;
  int lane = tid & 63;
  int w = tid >> 6, slot = w >> 1, half = w & 1;
  int n = blockIdx.x * 2 + slot;
  bool valid = (n < N);
  int p0 = 0, p1 = 0;
  if (valid) {
    p0 = offs[n];
    p1 = offs[n + 1];
  }
  float aS0 = 0.f, aS1 = 0.f;
  float aV00 = 0.f, aV01 = 0.f, aV10 = 0.f, aV11 = 0.f, aV20 = 0.f, aV21 = 0.f;
  int p = p0 + half;
  float4 c[4];
  bool has[4];
#pragma unroll
  for (int i = 0; i < 4; ++i) {
    has[i] = (p + 2 * i) < p1;
    if (has[i]) c[i] = pk[p + 2 * i];
  }
  while (has[0]) {
    uint g1[4], g2[4], g3[4], gv0[4], gv1[4], gv2[4], gt1[4], gt2[4], gt3[4];
#pragma unroll
    for (int i = 0; i < 4; ++i) {
      if (has[i]) {
        int bits = __float_as_int(c[i].x);
        int col = bits & 16383, ib = bits >> 14;
        const uint* hb = hn + (size_t)col * 192;
        const uint* vb = vbin + (size_t)col * 192;
        const uint* tb = tab + (size_t)ib * 192;
        g1[i] = hb[lane];
        g2[i] = hb[lane + 64];
        g3[i] = hb[lane + 128];
        gv0[i] = vb[lane];
        gv1[i] = vb[lane + 64];
        gv2[i] = vb[lane + 128];
        gt1[i] = tb[lane];
        gt2[i] = tb[lane + 64];
        gt3[i] = tb[lane + 128];
      }
    }
    int pn = p + 8;
    float4 nc[4];
    bool nhas[4];
#pragma unroll
    for (int i = 0; i < 4; ++i) {
      nhas[i] = (pn + 2 * i) < p1;
      if (nhas[i]) nc[i] = pk[pn + 2 * i];
    }
#pragma unroll
    for (int i = 0; i < 4; ++i) {
      if (has[i]) {
        aS0 += BFLO(g1[i]) * BFLO(gt1[i]);
        aS1 += BFHI(g1[i]) * BFHI(gt1[i]);
        float w2l = BFLO(g2[i]) * BFLO(gt2[i]), w2h = BFHI(g2[i]) * BFHI(gt2[i]);
        float w3l = BFLO(g3[i]) * BFLO(gt3[i]), w3h = BFHI(g3[i]) * BFHI(gt3[i]);
        aV00 += BFLO(gv0[i]) * w2l + w3l * c[i].y;
        aV01 += BFHI(gv0[i]) * w2h + w3h * c[i].y;
        aV10 += BFLO(gv1[i]) * w2l + w3l * c[i].z;
        aV11 += BFHI(gv1[i]) * w2h + w3h * c[i].z;
        aV20 += BFLO(gv2[i]) * w2l + w3l * c[i].w;
        aV21 += BFHI(gv2[i]) * w2h + w3h * c[i].w;
      }
    }
#pragma unroll
    for (int i = 0; i < 4; ++i) {
      c[i] = nc[i];
      has[i] = nhas[i];
    }
    p = pn;
  }
  if (half == 1) {
    float* r = &red[slot][lane][0];
    r[0] = aS0; r[1] = aS1;
    r[2] = aV00; r[3] = aV01;
    r[4] = aV10; r[5] = aV11;
    r[6] = aV20; r[7] = aV21;
  }
  __syncthreads();
  if (half == 0 && valid) {
    const float* r = &red[slot][lane][0];
    aS0 += r[0]; aS1 += r[1];
    aV00 += r[2]; aV01 += r[3];
    aV10 += r[4]; aV11 += r[5];
    aV20 += r[6]; aV21 += r[7];
    float2* sp = (float2*)(scalar + (size_t)n * 128) + lane;
    float2 s = *sp;
    s.x += aS0;
    s.y += aS1;
    *sp = s;
    ((uint*)(sbf + (size_t)n * 128))[lane] = (uint)f2bf(s.x) | ((uint)f2bf(s.y) << 16);
    float2* vp0 = (float2*)(vec + (size_t)n * 384) + lane;
    float2* vp1 = (float2*)(vec + (size_t)n * 384 + 128) + lane;
    float2* vp2 = (float2*)(vec + (size_t)n * 384 + 256) + lane;
    float2 v0 = *vp0, v1 = *vp1, v2 = *vp2;
    v0.x += aV00; v0.y += aV01;
    v1.x += aV10; v1.y += aV11;
    v2.x += aV20; v2.y += aV21;
    *vp0 = v0; *vp1 = v1; *vp2 = v2;
    uint* ob = (uint*)(vbout + (size_t)n * 384);
    ob[lane] = (uint)f2bf(v0.x) | ((uint)f2bf(v0.y) << 16);
    ob[lane + 64] = (uint)f2bf(v1.x) | ((uint)f2bf(v1.y) << 16);
    ob[lane + 128] = (uint)f2bf(v2.x) | ((uint)f2bf(v2.y) << 16);
  }
}

// ---------------- message MLP: hn = silu(sbf@W1^T+b1)@W2^T+b2 -> bf16 ----------------
__global__ __launch_bounds__(256) void mlp_kernel(const ushort* __restrict__ A,
                                                  const ushort* __restrict__ W1T,
                                                  const float* __restrict__ b1,
                                                  const ushort* __restrict__ W2T,
                                                  const float* __restrict__ b2,
                                                  ushort* __restrict__ out, int M) {
  __shared__ ushort As[32 * 128];
  __shared__ ushort Bs[128 * 128];
  __shared__ ushort Hs[32 * 128];
  int tid = threadIdx.x;
  int lane = tid & 63, w = tid >> 6;
  int mh = w >> 1, wc = w & 1;
  int m0 = blockIdx.x * 32;
  int cl = lane & 15, rq = lane >> 4;
  f32x4 acc[4] = {};
  {
#pragma unroll
    for (int r = 0; r < 2; ++r) {
      int c = tid + r * 256;
      int row = c >> 4, ch = c & 15;
      uint4 av = make_uint4(0, 0, 0, 0);
      if (m0 + row < M) av = *(const uint4*)(A + (size_t)(m0 + row) * 128 + ch * 8);
      *(uint4*)(&As[row * 128 + ((ch ^ (row & 7)) * 8)]) = av;
    }
#pragma unroll
    for (int r = 0; r < 8; ++r) {
      int c = tid + r * 256;
      int row = c >> 4, ch = c & 15;
      uint4 bv = *(const uint4*)(W1T + (size_t)row * 128 + ch * 8);
      *(uint4*)(&Bs[row * 128 + ((ch ^ (row & 7)) * 8)]) = bv;
    }
    __syncthreads();
#pragma unroll
    for (int ks = 0; ks < 4; ++ks) {
      int ch = ks * 4 + rq;
      int ra = mh * 16 + cl;
      bf16x8 a = *(bf16x8*)&As[ra * 128 + ((ch ^ (ra & 7)) * 8)];
#pragma unroll
      for (int ns = 0; ns < 4; ++ns) {
        int rb = wc * 64 + ns * 16 + cl;
        bf16x8 b = *(bf16x8*)&Bs[rb * 128 + ((ch ^ (rb & 7)) * 8)];
        acc[ns] = __builtin_amdgcn_mfma_f32_16x16x32_bf16(a, b, acc[ns], 0, 0, 0);
      }
    }
  }
#pragma unroll
  for (int ns = 0; ns < 4; ++ns) {
    int hcol = wc * 64 + ns * 16 + cl;
    float bv = b1[hcol];
    int chunk = hcol >> 3, el = hcol & 7;
#pragma unroll
    for (int j = 0; j < 4; ++j) {
      int hr = mh * 16 + rq * 4 + j;
      float v = silu_f(acc[ns][j] + bv);
      Hs[hr * 128 + ((chunk ^ (hr & 7)) * 8) + el] = f2bf(v);
    }
  }
  __syncthreads();
  for (int nt = 0; nt < 3; ++nt) {
#pragma unroll
    for (int r = 0; r < 8; ++r) {
      int c = tid + r * 256;
      int row = c >> 4, ch = c & 15;
      uint4 bv = *(const uint4*)(W2T + (size_t)(nt * 128 + row) * 128 + ch * 8);
      *(uint4*)(&Bs[row * 128 + ((ch ^ (row & 7)) * 8)]) = bv;
    }
    __syncthreads();
    f32x4 acc2[4] = {};
#pragma unroll
    for (int ks = 0; ks < 4; ++ks) {
      int ch = ks * 4 + rq;
      int ra = mh * 16 + cl;
      bf16x8 a = *(bf16x8*)&Hs[ra * 128 + ((ch ^ (ra & 7)) * 8)];
#pragma unroll
      for (int ns = 0; ns < 4; ++ns) {
        int rb = wc * 64 + ns * 16 + cl;
        bf16x8 b = *(bf16x8*)&Bs[rb * 128 + ((ch ^ (rb & 7)) * 8)];
        acc2[ns] = __builtin_amdgcn_mfma_f32_16x16x32_bf16(a, b, acc2[ns], 0, 0, 0);
      }
    }
#pragma unroll
    for (int ns = 0; ns < 4; ++ns) {
      int col = nt * 128 + wc * 64 + ns * 16 + cl;
      float bv = b2[col];
#pragma unroll
      for (int j = 0; j < 4; ++j) {
        int m = m0 + mh * 16 + rq * 4 + j;
        if (m >= M) continue;
        out[(size_t)m * 384 + col] = f2bf(acc2[ns][j] + bv);
      }
    }
    __syncthreads();
  }
}

// ---------------- fused update MLP + combine ----------------
__global__ __launch_bounds__(256) void mlp2_kernel(const ushort* __restrict__ sbf_in,
                                                   const ushort* __restrict__ W1T,
                                                   const float* __restrict__ b1,
                                                   const ushort* __restrict__ W2T,
                                                   const float* __restrict__ b2,
                                                   const ushort* __restrict__ uvvv,
                                                   float* __restrict__ scalar,
                                                   ushort* __restrict__ sbf,
                                                   float* __restrict__ vec,
                                                   ushort* __restrict__ vbf, int M) {
  __shared__ ushort As[32 * 128];
  __shared__ ushort Bs[128 * 128];
  __shared__ ushort Hs[32 * 128];
  int tid = threadIdx.x;
  int lane = tid & 63, w = tid >> 6;
  int mh = w >> 1, wc = w & 1;
  int m0 = blockIdx.x * 32;
  int cl = lane & 15, rq = lane >> 4;
  f32x4 acc[4] = {};
  for (int k0 = 0; k0 < 256; k0 += 128) {
    __syncthreads();
#pragma unroll
    for (int r = 0; r < 2; ++r) {
      int c = tid + r * 256;
      int row = c >> 4, ch = c & 15;
      uint4 av = make_uint4(0, 0, 0, 0);
      if (m0 + row < M) {
        if (k0 == 0) {
          av = *(const uint4*)(sbf_in + (size_t)(m0 + row) * 128 + ch * 8);
        } else {
          const ushort* ub = uvvv + (size_t)(m0 + row) * 768 + 128 + ch * 8;
          bf16x8 x0 = *(const bf16x8*)(ub);
          bf16x8 x1 = *(const bf16x8*)(ub + 256);
          bf16x8 x2 = *(const bf16x8*)(ub + 512);
          ushort pkv[8];
#pragma unroll
          for (int e = 0; e < 8; ++e) {
            float a = bf2f((ushort)x0[e]), bb = bf2f((ushort)x1[e]), cc = bf2f((ushort)x2[e]);
            pkv[e] = f2bf(sqrtf(a * a + bb * bb + cc * cc + 1e-8f));
          }
          av = *(uint4*)pkv;
        }
      }
      *(uint4*)(&As[row * 128 + ((ch ^ (row & 7)) * 8)]) = av;
    }
#pragma unroll
    for (int r = 0; r < 8; ++r) {
      int c = tid + r * 256;
      int row = c >> 4, ch = c & 15;
      uint4 bv = *(const uint4*)(W1T + (size_t)row * 256 + k0 + ch * 8);
      *(uint4*)(&Bs[row * 128 + ((ch ^ (row & 7)) * 8)]) = bv;
    }
    __syncthreads();
#pragma unroll
    for (int ks = 0; ks < 4; ++ks) {
      int ch = ks * 4 + rq;
      int ra = mh * 16 + cl;
      bf16x8 a = *(bf16x8*)&As[ra * 128 + ((ch ^ (ra & 7)) * 8)];
#pragma unroll
      for (int ns = 0; ns < 4; ++ns) {
        int rb = wc * 64 + ns * 16 + cl;
        bf16x8 b = *(bf16x8*)&Bs[rb * 128 + ((ch ^ (rb & 7)) * 8)];
        acc[ns] = __builtin_amdgcn_mfma_f32_16x16x32_bf16(a, b, acc[ns], 0, 0, 0);
      }
    }
  }
#pragma unroll
  for (int ns = 0; ns < 4; ++ns) {
    int hcol = wc * 64 + ns * 16 + cl;
    float bv = b1[hcol];
    int chunk = hcol >> 3, el = hcol & 7;
#pragma unroll
    for (int j = 0; j < 4; ++j) {
      int hr = mh * 16 + rq * 4 + j;
      float v = silu_f(acc[ns][j] + bv);
      Hs[hr * 128 + ((chunk ^ (hr & 7)) * 8) + el] = f2bf(v);
    }
  }
  __syncthreads();
  f32x4 aReg[3][4];
  for (int nt = 0; nt < 3; ++nt) {
#pragma unroll
    for (int r = 0; r < 8; ++r) {
      int c = tid + r * 256;
      int row = c >> 4, ch = c & 15;
      uint4 bv = *(const uint4*)(W2T + (size_t)(nt * 128 + row) * 128 + ch * 8);
      *(uint4*)(&Bs[row * 128 + ((ch ^ (row & 7)) * 8)]) = bv;
    }
    __syncthreads();
    f32x4 acc2[4] = {};
#pragma unroll
    for (int ks = 0; ks < 4; ++ks) {
      int ch = ks * 4 + rq;
      int ra = mh * 16 + cl;
      bf16x8 a = *(bf16x8*)&Hs[ra * 128 + ((ch ^ (ra & 7)) * 8)];
#pragma unroll
      for (int ns = 0; ns < 4; ++ns) {
        int rb = wc * 64 + ns * 16 + cl;
        bf16x8 b = *(bf16x8*)&Bs[rb * 128 + ((ch ^ (rb & 7)) * 8)];
        acc2[ns] = __builtin_amdgcn_mfma_f32_16x16x32_bf16(a, b, acc2[ns], 0, 0, 0);
      }
    }
#pragma unroll
    for (int ns = 0; ns < 4; ++ns) aReg[nt][ns] = acc2[ns];
    __syncthreads();
  }
#pragma unroll
  for (int ns = 0; ns < 4; ++ns) {
    int chOff = wc * 64 + ns * 16 + cl;
    float b2a = b2[chOff], b2b = b2[128 + chOff], b2c = b2[256 + chOff];
#pragma unroll
    for (int j = 0; j < 4; ++j) {
      int nn = m0 + mh * 16 + rq * 4 + j;
      if (nn >= M) continue;
      float a1 = aReg[0][ns][j] + b2a;
      float a2 = aReg[1][ns][j] + b2b;
      float a3 = aReg[2][ns][j] + b2c;
      const ushort* ub = uvvv + (size_t)nn * 768;
      float uv0 = bf2f(ub[chOff]), vv0 = bf2f(ub[128 + chOff]);
      float uv1 = bf2f(ub[256 + chOff]), vv1 = bf2f(ub[384 + chOff]);
      float uv2 = bf2f(ub[512 + chOff]), vv2 = bf2f(ub[640 + chOff]);
      float dot = uv0 * vv0 + uv1 * vv1 + uv2 * vv2;
      size_t si = (size_t)nn * 128 + chOff;
      float s = scalar[si] + a1 + a2 * dot;
      scalar[si] = s;
      sbf[si] = f2bf(s);
      size_t vb = (size_t)nn * 384 + chOff;
      float nv0 = vec[vb] + a3 * uv0;
      float nv1 = vec[vb + 128] + a3 * uv1;
      float nv2 = vec[vb + 256] + a3 * uv2;
      vec[vb] = nv0;
      vec[vb + 128] = nv1;
      vec[vb + 256] = nv2;
      vbf[vb] = f2bf(nv0);
      vbf[vb + 128] = f2bf(nv1);
      vbf[vb + 256] = f2bf(nv2);
    }
  }
}

// ---------------- bf16 MFMA GEMM: C = A[M,K] @ WT[N,K]^T -> bf16 ----------------
__global__ __launch_bounds__(256) void gemm_kernel(const ushort* __restrict__ A,
                                                   const ushort* __restrict__ WT,
                                                   ushort* __restrict__ Cout, int M, int K,
                                                   int Nn) {
  __shared__ ushort As[64 * 128];
  __shared__ ushort Bs[64 * 128];
  int tid = threadIdx.x;
  int m0 = blockIdx.x * 64, n0 = blockIdx.y * 64;
  int lane = tid & 63, w = tid >> 6, wr = w >> 1, wc = w & 1;
  f32x4 acc[2][2] = {};
  for (int k0 = 0; k0 < K; k0 += 128) {
    __syncthreads();
#pragma unroll
    for (int r = 0; r < 4; ++r) {
      int c = tid + r * 256;
      int row = c >> 4, col16 = c & 15;
      uint4 av = make_uint4(0, 0, 0, 0);
      if (m0 + row < M) av = *(const uint4*)(A + (size_t)(m0 + row) * K + k0 + col16 * 8);
      *(uint4*)(&As[row * 128 + ((col16 ^ (row & 7)) * 8)]) = av;
      uint4 bv = *(const uint4*)(WT + (size_t)(n0 + row) * K + k0 + col16 * 8);
      *(uint4*)(&Bs[row * 128 + ((col16 ^ (row & 7)) * 8)]) = bv;
    }
    __syncthreads();
#pragma unroll
    for (int ks = 0; ks < 4; ++ks) {
      int ch = ks * 4 + (lane >> 4);
      int ra0 = wr * 32 + (lane & 15), ra1 = ra0 + 16;
      int rb0 = wc * 32 + (lane & 15), rb1 = rb0 + 16;
      bf16x8 a0 = *(bf16x8*)&As[ra0 * 128 + ((ch ^ (ra0 & 7)) * 8)];
      bf16x8 a1 = *(bf16x8*)&As[ra1 * 128 + ((ch ^ (ra1 & 7)) * 8)];
      bf16x8 b0 = *(bf16x8*)&Bs[rb0 * 128 + ((ch ^ (rb0 & 7)) * 8)];
      bf16x8 b1 = *(bf16x8*)&Bs[rb1 * 128 + ((ch ^ (rb1 & 7)) * 8)];
      acc[0][0] = __builtin_amdgcn_mfma_f32_16x16x32_bf16(a0, b0, acc[0][0], 0, 0, 0);
      acc[0][1] = __builtin_amdgcn_mfma_f32_16x16x32_bf16(a0, b1, acc[0][1], 0, 0, 0);
      acc[1][0] = __builtin_amdgcn_mfma_f32_16x16x32_bf16(a1, b0, acc[1][0], 0, 0, 0);
      acc[1][1] = __builtin_amdgcn_mfma_f32_16x16x32_bf16(a1, b1, acc[1][1], 0, 0, 0);
    }
  }
  int cl = lane & 15, rq = lane >> 4;
#pragma unroll
  for (int ms = 0; ms < 2; ++ms)
#pragma unroll
    for (int ns = 0; ns < 2; ++ns) {
      int n = n0 + wc * 32 + ns * 16 + cl;
#pragma unroll
      for (int j = 0; j < 4; ++j) {
        int m = m0 + wr * 32 + ms * 16 + rq * 4 + j;
        if (m >= M) continue;
        Cout[(size_t)m * Nn + n] = f2bf(acc[ms][ns][j]);
      }
    }
}

// ---------------- fused readout: silu(sbf@r1T+b1)·r_w2 + segment sum ----------------
__global__ __launch_bounds__(256) void readout_kernel(
    const ushort* __restrict__ sbf, const ushort* __restrict__ r1T, const float* __restrict__ rb1,
    const float* __restrict__ r_w2, const float* __restrict__ r_b2, const int* __restrict__ bidx,
    float* __restrict__ out, int N, int G) {
  __shared__ ushort As[64 * 128];
  __shared__ ushort Bs[64 * 128];
  __shared__ float rs[64];
  __shared__ float sm[64];
  int tid = threadIdx.x;
  int m0 = blockIdx.x * 64;
  int lane = tid & 63, w = tid >> 6, wr = w >> 1, wc = w & 1;
  int cl = lane & 15, rq = lane >> 4;
#pragma unroll
  for (int r = 0; r < 4; ++r) {
    int c = tid + r * 256;
    int row = c >> 4, ch = c & 15;
    uint4 av = make_uint4(0, 0, 0, 0);
    if (m0 + row < N) av = *(const uint4*)(sbf + (size_t)(m0 + row) * 128 + ch * 8);
    *(uint4*)(&As[row * 128 + ((ch ^ (row & 7)) * 8)]) = av;
    uint4 bv = *(const uint4*)(r1T + (size_t)row * 128 + ch * 8);
    *(uint4*)(&Bs[row * 128 + ((ch ^ (row & 7)) * 8)]) = bv;
  }
  if (tid < 64) {
    rs[tid] = 0.f;
    sm[tid] = 0.f;
  }
  __syncthreads();
  f32x4 acc[2][2] = {};
#pragma unroll
  for (int ks = 0; ks < 4; ++ks) {
    int ch = ks * 4 + rq;
    int ra0 = wr * 32 + cl, ra1 = ra0 + 16;
    int rb0 = wc * 32 + cl, rb1 = rb0 + 16;
    bf16x8 a0 = *(bf16x8*)&As[ra0 * 128 + ((ch ^ (ra0 & 7)) * 8)];
    bf16x8 a1 = *(bf16x8*)&As[ra1 * 128 + ((ch ^ (ra1 & 7)) * 8)];
    bf16x8 b0 = *(bf16x8*)&Bs[rb0 * 128 + ((ch ^ (rb0 & 7)) * 8)];
    bf16x8 b1 = *(bf16x8*)&Bs[rb1 * 128 + ((ch ^ (rb1 & 7)) * 8)];
    acc[0][0] = __builtin_amdgcn_mfma_f32_16x16x32_bf16(a0, b0, acc[0][0], 0, 0, 0);
    acc[0][1] = __builtin_amdgcn_mfma_f32_16x16x32_bf16(a0, b1, acc[0][1], 0, 0, 0);
    acc[1][0] = __builtin_amdgcn_mfma_f32_16x16x32_bf16(a1, b0, acc[1][0], 0, 0, 0);
    acc[1][1] = __builtin_amdgcn_mfma_f32_16x16x32_bf16(a1, b1, acc[1][1], 0, 0, 0);
  }
#pragma unroll
  for (int ms = 0; ms < 2; ++ms) {
    float part0 = 0.f, part1 = 0.f, part2 = 0.f, part3 = 0.f;
#pragma unroll
    for (int ns = 0; ns < 2; ++ns) {
      int col = wc * 32 + ns * 16 + cl;
      float b1v = rb1[col], wv = r_w2[col];
      part0 += silu_f(acc[ms][ns][0] + b1v) * wv;
      part1 += silu_f(acc[ms][ns][1] + b1v) * wv;
      part2 += silu_f(acc[ms][ns][2] + b1v) * wv;
      part3 += silu_f(acc[ms][ns][3] + b1v) * wv;
    }
#pragma unroll
    for (int o = 1; o < 16; o <<= 1) {
      part0 += __shfl_xor(part0, o);
      part1 += __shfl_xor(part1, o);
      part2 += __shfl_xor(part2, o);
      part3 += __shfl_xor(part3, o);
    }
    if (cl == 0) {
      int rbase = wr * 32 + ms * 16 + rq * 4;
      atomicAdd(&rs[rbase + 0], part0);
      atomicAdd(&rs[rbase + 1], part1);
      atomicAdd(&rs[rbase + 2], part2);
      atomicAdd(&rs[rbase + 3], part3);
    }
  }
  __syncthreads();
  float rb2 = r_b2[0];
  if (tid < 64) {
    int m = m0 + tid;
    if (m < N) atomicAdd(&sm[bidx[m]], rs[tid] + rb2);
  }
  __syncthreads();
  if (tid < G && G <= 64) atomicAdd(&out[tid], sm[tid]);
}

extern "C" void kernel_launch(void* const* d_in, const int* in_sizes, int n_in, void* d_out,
                              int out_size, void* d_ws, size_t ws_size, hipStream_t stream) {
  const int N = in_sizes[0];
  const int E = in_sizes[2] / 2;
  const int G = out_size;

  const int* z = (const int*)d_in[0];
  const float* pos = (const float*)d_in[1];
  const int* ei = (const int*)d_in[2];
  const float* shifts = (const float*)d_in[3];
  const int* bidx = (const int*)d_in[4];
  const float* emb = (const float*)d_in[5];
  const float* m_w1 = (const float*)d_in[6];
  const float* m_b1 = (const float*)d_in[7];
  const float* m_w2 = (const float*)d_in[8];
  const float* m_b2 = (const float*)d_in[9];
  const float* f_w = (const float*)d_in[10];
  const float* f_b = (const float*)d_in[11];
  const float* u_w = (const float*)d_in[12];
  const float* v_w = (const float*)d_in[13];
  const float* up_w1 = (const float*)d_in[14];
  const float* up_b1 = (const float*)d_in[15];
  const float* up_w2 = (const float*)d_in[16];
  const float* up_b2 = (const float*)d_in[17];
  const float* r_w1 = (const float*)d_in[18];
  const float* r_b1 = (const float*)d_in[19];
  const float* r_w2 = (const float*)d_in[20];
  const float* r_b2 = (const float*)d_in[21];
  float* out = (float*)d_out;

  float* w = (float*)d_ws;
  size_t off = 0;
  auto alloc = [&](size_t nfl) { float* p = w + off; off += (nfl + 3) & ~(size_t)3; return p; };
  ushort* tab = (ushort*)alloc((size_t)3 * TL * 192);
  float* scalar = alloc((size_t)N * 128);
  ushort* sbf = (ushort*)alloc((size_t)N * 64);
  float* vec = alloc((size_t)N * 384);
  ushort* mirA = (ushort*)alloc((size_t)N * 192);
  ushort* mirB = (ushort*)alloc((size_t)N * 192);
  ushort* hn_bf = (ushort*)alloc((size_t)N * 192);
  ushort* uvvv = (ushort*)alloc((size_t)N * 384);
  float* pkf = alloc((size_t)E * 4);
  ushort* wt = (ushort*)alloc((size_t)274432);
  int* counts = (int*)alloc((size_t)N);
  int* offs = (int*)alloc((size_t)N + 4);
  int* cursor = (int*)alloc((size_t)N);
  if (off * sizeof(float) > ws_size) return;

  hipMemsetAsync(counts, 0, (size_t)N * sizeof(int), stream);
  hipMemsetAsync(vec, 0, (size_t)N * 384 * sizeof(float), stream);
  hipMemsetAsync(mirA, 0, (size_t)N * 384 * sizeof(ushort), stream);
  hipMemsetAsync(out, 0, (size_t)G * sizeof(float), stream);

  int nbTable = 3 * (TL / 8);
  int nbEmb = (N * 128 + 383) / 384;
  int nbW = (548864 + 383) / 384;
  int nbCount = (E + 383) / 384;
  setup_kernel<<<nbTable + nbEmb + nbW + nbCount, 384, 0, stream>>>(
      z, emb, scalar, sbf, m_w1, m_w2, u_w, v_w, up_w1, up_w2, r_w1, wt, f_w, f_b, tab, pos, ei,
      shifts, counts, N, E);
  scan_kernel<<<1, 1024, 0, stream>>>(counts, offs, cursor, N);
  fill_kernel<<<(E + 255) / 256, 256, 0, stream>>>(pos, ei, shifts, cursor, (float4*)pkf, E);

  dim3 gm((N + 31) / 32);
  dim3 g3((3 * N + 63) / 64, 4);

  for (int l = 0; l < 3; l++) {
    ushort* mir_in = (l & 1) ? mirB : mirA;
    ushort* mir_out = (l & 1) ? mirA : mirB;
    const ushort* wl = wt + (size_t)l * 180224;
    mlp_kernel<<<gm, 256, 0, stream>>>(sbf, wl, m_b1 + l * 128, wl + 16384, m_b2 + l * 384,
                                       hn_bf, N);
    message_kernel<<<(N + 1) / 2, 256, 0, stream>>>(offs, (const float4*)pkf, (const uint*)hn_bf,
                                                    (const uint*)mir_in,
                                                    (const uint*)(tab + (size_t)l * TL * 384),
                                                    scalar, sbf, vec, mir_out, N);
    gemm_kernel<<<g3, 256, 0, stream>>>(mir_out, wl + 65536, uvvv, 3 * N, 128, 256);
    mlp2_kernel<<<gm, 256, 0, stream>>>(sbf, wl + 98304, up_b1 + l * 128, wl + 131072,
                                        up_b2 + l * 384, uvvv, scalar, sbf, vec, mir_out, N);
  }

  readout_kernel<<<(N + 63) / 64, 256, 0, stream>>>(sbf, wt + 540672, r_b1, r_w2, r_b2, bidx,
                                                    out, N, G);
}